// Round 12
// baseline (386.364 us; speedup 1.0000x reference)
//
#include <hip/hip_runtime.h>
#include <math.h>

constexpr int NPIX  = 262144;   // 512*512
constexpr int NLAB  = 8;
constexpr int NITER = 5;        // Newton-Schulz iterations (e0<=0.6 -> e5 < 1e-10)

// ---------------- workspace layout (float offsets), runtime nblk ----------------
__host__ __device__ inline size_t offMpart()         { return 0; }
__host__ __device__ inline size_t offSpart(int nblk) { return (size_t)2*nblk*8*4096; }
__host__ __device__ inline size_t offCnt(int nblk)   { return offSpart(nblk) + (size_t)2*nblk*8*64; }
__host__ __device__ inline size_t offMR(int nblk)    { return offCnt(nblk) + (size_t)2*nblk*8; }
__host__ __device__ inline size_t offSR(int nblk)    { return offMR(nblk) + 2*8*4096; }
__host__ __device__ inline size_t offCR(int nblk)    { return offSR(nblk) + 2*8*64; }
__host__ __device__ inline size_t offWH(int nblk)    { return offCR(nblk) + 16; }
__host__ __device__ inline size_t offCO(int nblk)    { return offWH(nblk) + 8*4096; }
__host__ __device__ inline size_t offT(int nblk)     { return offCO(nblk) + 8*4096; }
__host__ __device__ inline size_t offBIAS(int nblk)  { return offT(nblk) + 8*4096; }
__host__ __device__ inline size_t offMUC(int nblk)   { return offBIAS(nblk) + 8*64; }
__host__ __device__ inline size_t offMUS(int nblk)   { return offMUC(nblk) + 8*64; }
__host__ __device__ inline size_t offVALID(int nblk) { return offMUS(nblk) + 8*64; }

// =====================================================================
// K1: single-pass per-label moments. grid (nblk, 2 tensors), block 512.
// 8 waves/block; wave w owns label w's 64x64 accumulator (8x8/lane).
// Pixels staged 256/phase into xs[px][64] with XOR-4 column swizzle so
// staging writes are 4-way and compute b128 reads are 2-way (free).
// Single pixel per ballot iteration (~122 live VGPR, fits the 128 cap
// of launch_bounds(512,2) -> no spill, 2 blocks/CU at nblk=256).
// =====================================================================
__global__ __launch_bounds__(512, 2) void k_moments(
    const float* __restrict__ cont, const float* __restrict__ styl,
    const int* __restrict__ cseg, const int* __restrict__ sseg,
    float* __restrict__ ws, int nblk)
{
  const int t = blockIdx.y, blk = blockIdx.x;
  const float* __restrict__ X  = t ? styl : cont;
  const int*  __restrict__ seg = t ? sseg : cseg;
  const int tid = threadIdx.x, lane = tid & 63, wv = tid >> 6;

  __shared__ float xs[256 * 64];   // exactly 64 KB

  const int r0 = (lane >> 3) << 3;
  const int c0 = (lane & 7) << 3;

  float acc[8][8];
  #pragma unroll
  for (int i = 0; i < 8; ++i)
    #pragma unroll
    for (int j = 0; j < 8; ++j) acc[i][j] = 0.f;
  float ssum = 0.f;
  int   cnt  = 0;

  const int chunk = NPIX / nblk;
  const int pbase = blk * chunk;
  const int nph   = chunk >> 8;
  const int ci  = tid >> 5;             // 0..15
  const int pxi = (tid & 31) << 2;      // 0..124
  const int swW = (tid & 7) << 2;       // staging column swizzle (bits 2..4)

  for (int ph = 0; ph < nph; ++ph) {
    const int p0 = pbase + (ph << 8);
    float4 v[8];
    #pragma unroll
    for (int q = 0; q < 8; ++q) {
      const int c  = ci + ((q & 3) << 4);
      const int px = pxi + ((q >> 2) << 7);
      v[q] = *reinterpret_cast<const float4*>(&X[(size_t)c * NPIX + p0 + px]);
    }
    int lb[4];
    #pragma unroll
    for (int g = 0; g < 4; ++g) lb[g] = seg[p0 + (g << 6) + lane];

    __syncthreads();   // previous phase reads done
    #pragma unroll
    for (int q = 0; q < 8; ++q) {
      const int c  = ci + ((q & 3) << 4);
      const int px = pxi + ((q >> 2) << 7);
      const int pc = c ^ swW;
      xs[(px + 0) * 64 + pc] = v[q].x;
      xs[(px + 1) * 64 + pc] = v[q].y;
      xs[(px + 2) * 64 + pc] = v[q].z;
      xs[(px + 3) * 64 + pc] = v[q].w;
    }
    __syncthreads();   // staging visible

    for (int g = 0; g < 4; ++g) {
      unsigned long long m = __ballot(lb[g] == wv);
      cnt += __popcll(m);
      while (m) {
        const int j = (g << 6) + __builtin_ctzll(m);
        m &= m - 1;
        const int sw = j & 28;           // ((j>>2)&7)<<2
        const float4 a0 = *reinterpret_cast<const float4*>(&xs[j * 64 + (r0 ^ sw)]);
        const float4 a1 = *reinterpret_cast<const float4*>(&xs[j * 64 + ((r0 ^ sw) ^ 4)]);
        const float4 b0 = *reinterpret_cast<const float4*>(&xs[j * 64 + (c0 ^ sw)]);
        const float4 b1 = *reinterpret_cast<const float4*>(&xs[j * 64 + ((c0 ^ sw) ^ 4)]);
        ssum += xs[j * 64 + (lane ^ sw)];
        const float av[8] = {a0.x, a0.y, a0.z, a0.w, a1.x, a1.y, a1.z, a1.w};
        const float bv[8] = {b0.x, b0.y, b0.z, b0.w, b1.x, b1.y, b1.z, b1.w};
        #pragma unroll
        for (int i = 0; i < 8; ++i)
          #pragma unroll
          for (int jj = 0; jj < 8; ++jj) acc[i][jj] += av[i] * bv[jj];
      }
    }
  }

  // flush partials (logical indexing)
  float* Md = ws + offMpart() + (size_t)((t * nblk + blk) * 8 + wv) * 4096;
  #pragma unroll
  for (int i = 0; i < 8; ++i) {
    *reinterpret_cast<float4*>(&Md[(r0 + i) * 64 + c0]) =
        make_float4(acc[i][0], acc[i][1], acc[i][2], acc[i][3]);
    *reinterpret_cast<float4*>(&Md[(r0 + i) * 64 + c0 + 4]) =
        make_float4(acc[i][4], acc[i][5], acc[i][6], acc[i][7]);
  }
  ws[offSpart(nblk) + (size_t)((t * nblk + blk) * 8 + wv) * 64 + lane] = ssum;
  if (lane == 0) ws[offCnt(nblk) + (size_t)(t * nblk + blk) * 8 + wv] = (float)cnt;
}

// =====================================================================
// K1b: reduce partials over nblk. grid (256, 8 chunks) = 2048 blocks,
// 4 independent accumulators, atomicAdd combine (MR/SR/CR pre-zeroed).
// r9: 123us -> off top-5.
// =====================================================================
__global__ __launch_bounds__(256) void k_reduce(float* __restrict__ ws, int nblk)
{
  const int b = blockIdx.x;
  const int sgm = b & 15, tl = b >> 4, l = tl & 7, t = tl >> 3;
  const int tid = threadIdx.x;
  const int clen = nblk >> 3;                 // nblk is pow2 >= 8
  const int c0 = blockIdx.y * clen, c1 = c0 + clen;
  const size_t stride = (size_t)8 * 4096;
  const float* src = ws + offMpart() + (size_t)(t * nblk) * stride + (size_t)l * 4096 + sgm * 256 + tid;
  float s0 = 0.f, s1 = 0.f, s2 = 0.f, s3 = 0.f;
  int bb = c0;
  for (; bb + 3 < c1; bb += 4) {
    s0 += src[(size_t)(bb + 0) * stride];
    s1 += src[(size_t)(bb + 1) * stride];
    s2 += src[(size_t)(bb + 2) * stride];
    s3 += src[(size_t)(bb + 3) * stride];
  }
  for (; bb < c1; ++bb) s0 += src[(size_t)bb * stride];
  atomicAdd(&ws[offMR(nblk) + (size_t)tl * 4096 + sgm * 256 + tid], (s0 + s1) + (s2 + s3));
  if (sgm == 0) {
    if (tid < 64) {
      float q0 = 0.f, q1 = 0.f;
      int b2 = c0;
      for (; b2 + 1 < c1; b2 += 2) {
        q0 += ws[offSpart(nblk) + (size_t)((t * nblk + b2) * 8 + l) * 64 + tid];
        q1 += ws[offSpart(nblk) + (size_t)((t * nblk + b2 + 1) * 8 + l) * 64 + tid];
      }
      for (; b2 < c1; ++b2)
        q0 += ws[offSpart(nblk) + (size_t)((t * nblk + b2) * 8 + l) * 64 + tid];
      atomicAdd(&ws[offSR(nblk) + tl * 64 + tid], q0 + q1);
    } else if (tid == 64) {
      float q = 0.f;
      for (int b2 = c0; b2 < c1; ++b2)
        q += ws[offCnt(nblk) + (size_t)(t * nblk + b2) * 8 + l];
      atomicAdd(&ws[offCR(nblk) + tl], q);
    }
  }
}

// =====================================================================
// 64x64 matmul, operands symmetric (A[r][k] read as A[k][r], row-k b128).
// Block 512 (8 waves -> 2 waves/SIMD for latency hiding).
// Each lane owns a 2x4 tile: rows r0,r0+1, cols c0..c0+3.
// =====================================================================
__device__ __forceinline__ void mm64x8(float* __restrict__ dst,
    const float* __restrict__ A, const float* __restrict__ B,
    int tid, float p0, float p1)
{
  const int r0 = (tid >> 4) << 1;       // 0,2,...,62
  const int c0 = (tid & 15) << 2;       // 0,4,...,60
  float acc[2][4];
  #pragma unroll
  for (int i = 0; i < 2; ++i)
    #pragma unroll
    for (int j = 0; j < 4; ++j) acc[i][j] = 0.f;
  #pragma unroll 4
  for (int k = 0; k < 64; ++k) {
    const float2 a = *reinterpret_cast<const float2*>(&A[k * 64 + r0]);
    const float4 b = *reinterpret_cast<const float4*>(&B[k * 64 + c0]);
    acc[0][0] += a.x * b.x; acc[0][1] += a.x * b.y;
    acc[0][2] += a.x * b.z; acc[0][3] += a.x * b.w;
    acc[1][0] += a.y * b.x; acc[1][1] += a.y * b.y;
    acc[1][2] += a.y * b.z; acc[1][3] += a.y * b.w;
  }
  #pragma unroll
  for (int i = 0; i < 2; ++i) {
    float4 o;
    o.x = p1 * acc[i][0] + (((r0 + i) == (c0 + 0)) ? p0 : 0.f);
    o.y = p1 * acc[i][1] + (((r0 + i) == (c0 + 1)) ? p0 : 0.f);
    o.z = p1 * acc[i][2] + (((r0 + i) == (c0 + 2)) ? p0 : 0.f);
    o.w = p1 * acc[i][3] + (((r0 + i) == (c0 + 3)) ? p0 : 0.f);
    *reinterpret_cast<float4*>(&dst[(r0 + i) * 64 + c0]) = o;
  }
}

// =====================================================================
// K2: cov build + coupled Newton-Schulz. grid 16 (t*8+l), block 512.
// t=0: WH = (cov_c+I)^-1/2 ; t=1: CO = cov_s^1/2
// =====================================================================
__global__ __launch_bounds__(512) void k_ns(float* __restrict__ ws, int nblk)
{
  const int l = blockIdx.x & 7, t = blockIdx.x >> 3;
  const int tid = threadIdx.x;
  __shared__ float bA[4096], bY[4096], bZ[4096], bT[4096];  // exactly 64 KB
  float* svec   = bT;        // scratch aliases, consumed before chain starts
  float* scal   = bT + 128;

  const float n0 = ws[offCR(nblk) + l];
  const float n1 = ws[offCR(nblk) + 8 + l];
  const float n = t ? n1 : n0;
  const bool valid = (n0 > 10.f) && (n1 > 10.f) && (n0 < 100.f * n1) && (n1 < 100.f * n0);
  if (tid < 64) svec[tid] = ws[offSR(nblk) + (t * 8 + l) * 64 + tid];
  __syncthreads();

  const float invn = 1.f / fmaxf(n, 1.f);
  const float nm1  = n - 1.f;
  const float rdiv = 1.f / ((nm1 == 0.f) ? 1e-5f : nm1);
  const int i0 = tid >> 3, jb = (tid & 7) << 3;   // 512 threads: 8 floats each
  const float Si = svec[i0];
  const float* MRp = ws + offMR(nblk) + (size_t)(t * 8 + l) * 4096;
  #pragma unroll
  for (int q = 0; q < 2; ++q) {
    const int j = jb + (q << 2);
    const float4 m  = *reinterpret_cast<const float4*>(&MRp[i0 * 64 + j]);
    const float4 sj = *reinterpret_cast<const float4*>(&svec[j]);
    float4 a;
    a.x = (m.x - Si * sj.x * invn) * rdiv + ((t == 0 && i0 == j + 0) ? 1.f : 0.f);
    a.y = (m.y - Si * sj.y * invn) * rdiv + ((t == 0 && i0 == j + 1) ? 1.f : 0.f);
    a.z = (m.z - Si * sj.z * invn) * rdiv + ((t == 0 && i0 == j + 2) ? 1.f : 0.f);
    a.w = (m.w - Si * sj.w * invn) * rdiv + ((t == 0 && i0 == j + 3) ? 1.f : 0.f);
    *reinterpret_cast<float4*>(&bA[i0 * 64 + j]) = a;
  }
  if (tid < 64) ws[(t ? offMUS(nblk) : offMUC(nblk)) + l * 64 + tid] = svec[tid] * invn;
  if (t == 0 && tid == 0) ws[offVALID(nblk) + l] = valid ? 1.f : 0.f;
  __syncthreads();

  if (tid < 64) {   // Gershgorin row sums (column read, bA exactly symmetric)
    float s = 0.f;
    for (int j = 0; j < 64; ++j) s += fabsf(bA[j * 64 + tid]);
    #pragma unroll
    for (int o = 32; o; o >>= 1) s = fmaxf(s, __shfl_xor(s, o));  // wave-parallel max
    if (tid == 0) scal[0] = fmaxf(s, 1e-20f);
  }
  __syncthreads();
  const float cval = scal[0];
  const float rc = 1.f / cval;

  #pragma unroll
  for (int q = 0; q < 2; ++q) {   // Y = A/c, Z = I
    const int j = jb + (q << 2);
    float4 a = *reinterpret_cast<const float4*>(&bA[i0 * 64 + j]);
    a.x *= rc; a.y *= rc; a.z *= rc; a.w *= rc;
    *reinterpret_cast<float4*>(&bY[i0 * 64 + j]) = a;
    float4 z;
    z.x = (i0 == j + 0) ? 1.f : 0.f; z.y = (i0 == j + 1) ? 1.f : 0.f;
    z.z = (i0 == j + 2) ? 1.f : 0.f; z.w = (i0 == j + 3) ? 1.f : 0.f;
    *reinterpret_cast<float4*>(&bZ[i0 * 64 + j]) = z;
  }
  __syncthreads();

  float *Y = bY, *Z = bZ, *T = bT, *Wb = bA;
  for (int it = 0; it < NITER; ++it) {
    mm64x8(T, Z, Y, tid, 1.5f, -0.5f); __syncthreads();
    mm64x8(Wb, Y, T, tid, 0.f, 1.f);   __syncthreads();
    mm64x8(Y, T, Z, tid, 0.f, 1.f);    __syncthreads();
    float* nz = Y; Y = Wb; Wb = Z; Z = nz;
  }

  const float osc = t ? sqrtf(cval) : (1.0f / sqrtf(cval));
  const float* src = t ? Y : Z;
  float* dst = ws + (t ? offCO(nblk) : offWH(nblk)) + (size_t)l * 4096;
  #pragma unroll
  for (int q = 0; q < 2; ++q) {
    const int j = jb + (q << 2);
    float4 v = *reinterpret_cast<const float4*>(&src[i0 * 64 + j]);
    v.x *= osc; v.y *= osc; v.z *= osc; v.w *= osc;
    *reinterpret_cast<float4*>(&dst[i0 * 64 + j]) = v;
  }
}

// =====================================================================
// K2b: T_l = CO_l @ WH_l (identity if invalid), bias_l = mus - T@muc (0 if invalid)
// =====================================================================
__global__ __launch_bounds__(256) void k_tmat(float* __restrict__ ws, int nblk)
{
  const int l = blockIdx.x;
  const int tid = threadIdx.x;
  __shared__ float Am[4096], Bm[4096];
  __shared__ float red[64];
  __shared__ float mucS[64], musS[64];
  const bool valid = ws[offVALID(nblk) + l] > 0.5f;
  if (tid < 64) {
    red[tid] = 0.f;
    mucS[tid] = ws[offMUC(nblk) + l * 64 + tid];
    musS[tid] = ws[offMUS(nblk) + l * 64 + tid];
  }
  #pragma unroll
  for (int q = 0; q < 4; ++q) {
    const int e = tid * 4 + q * 1024;
    *reinterpret_cast<float4*>(&Am[e]) =
        *reinterpret_cast<const float4*>(&ws[offCO(nblk) + (size_t)l * 4096 + e]);
    *reinterpret_cast<float4*>(&Bm[e]) =
        *reinterpret_cast<const float4*>(&ws[offWH(nblk) + (size_t)l * 4096 + e]);
  }
  __syncthreads();
  const int lane = tid & 63, wv = tid >> 6;
  const int r0 = (wv << 4) + ((lane >> 4) << 2);
  const int c0 = (lane & 15) << 2;
  float acc[4][4];
  #pragma unroll
  for (int i = 0; i < 4; ++i)
    #pragma unroll
    for (int j = 0; j < 4; ++j) acc[i][j] = 0.f;
  #pragma unroll 4
  for (int k = 0; k < 64; ++k) {
    const float4 a = *reinterpret_cast<const float4*>(&Am[k * 64 + r0]);  // CO symmetric
    const float4 b = *reinterpret_cast<const float4*>(&Bm[k * 64 + c0]);
    const float av[4] = {a.x, a.y, a.z, a.w};
    const float bv[4] = {b.x, b.y, b.z, b.w};
    #pragma unroll
    for (int i = 0; i < 4; ++i)
      #pragma unroll
      for (int j = 0; j < 4; ++j) acc[i][j] += av[i] * bv[j];
  }
  float* Td = ws + offT(nblk) + (size_t)l * 4096;
  #pragma unroll
  for (int i = 0; i < 4; ++i) {
    float4 o;
    o.x = valid ? acc[i][0] : (((r0 + i) == (c0 + 0)) ? 1.f : 0.f);
    o.y = valid ? acc[i][1] : (((r0 + i) == (c0 + 1)) ? 1.f : 0.f);
    o.z = valid ? acc[i][2] : (((r0 + i) == (c0 + 2)) ? 1.f : 0.f);
    o.w = valid ? acc[i][3] : (((r0 + i) == (c0 + 3)) ? 1.f : 0.f);
    *reinterpret_cast<float4*>(&Td[(r0 + i) * 64 + c0]) = o;
    const float bp = o.x * mucS[c0] + o.y * mucS[c0 + 1] + o.z * mucS[c0 + 2] + o.w * mucS[c0 + 3];
    atomicAdd(&red[r0 + i], bp);
  }
  __syncthreads();
  if (tid < 64) ws[offBIAS(nblk) + l * 64 + tid] = valid ? (musS[tid] - red[tid]) : 0.f;
}

// =====================================================================
// K3: apply y = T_lab x + bias_lab. Same-label PAIRS via counting sort
// (512-px window, grid exactly 512). r11 failed because the compiler
// SANK the 32 float4 loads into the q-loop (VGPR=88, 4x re-load of
// uncoalesced gathers). r12 fix: asm volatile pins after the DECLs
// force the loads to complete ONCE into registers (rule-#17 tool).
// Expect VGPR ~170 (1 block/CU) with FETCH unchanged (no spill), and
// the halved LDS T-read count (5 issuing waves x 1024 b128) to pay off.
// =====================================================================
__global__ __launch_bounds__(512, 2) void k_apply(
    const float* __restrict__ cont, const int* __restrict__ cseg,
    const float* __restrict__ ws, float* __restrict__ out, int nblk)
{
  const int tid = threadIdx.x;
  const int base = blockIdx.x * 512;
  __shared__ float Tq[8 * 1028];       // one 16-oc quarter, 8 labels
  __shared__ float biasS[8 * 66];
  __shared__ int labw[512];
  __shared__ unsigned short sidx[520];
  __shared__ int cnt8[8], cur8[8], offs8[8], npS;

  if (tid < 8) cnt8[tid] = 0;
  biasS[(tid >> 6) * 66 + (tid & 63)] = ws[offBIAS(nblk) + tid];
  __syncthreads();
  {
    const int lb = cseg[base + tid];
    labw[tid] = lb;
    atomicAdd(&cnt8[lb], 1);
  }
  __syncthreads();
  if (tid == 0) {
    int off = 0;
    for (int l2 = 0; l2 < 8; ++l2) {
      offs8[l2] = off; cur8[l2] = off;
      off += cnt8[l2] + (cnt8[l2] & 1);
    }
    npS = off >> 1;
  }
  __syncthreads();
  {
    const int pos = atomicAdd(&cur8[labw[tid]], 1);
    sidx[pos] = (unsigned short)tid;
  }
  __syncthreads();
  if (tid < 8 && (cnt8[tid] & 1))
    sidx[offs8[tid] + cnt8[tid]] = sidx[offs8[tid]];   // duplicate-pad odd runs
  __syncthreads();

  const int np = npS;                  // 256..260
  const bool act = tid < np;
  int p0 = base, p1 = base, lab = 0;
  if (act) {
    const int i0 = sidx[2 * tid], i1 = sidx[2 * tid + 1];
    lab = labw[i0];
    p0 = base + i0; p1 = base + i1;
  }

  // x vectors for both pixels as 32 NAMED float4s — loads unconditional
  // (inactive threads read pixel `base`, harmless), then PINNED so the
  // compiler cannot sink/rematerialize them into the q-loop (r11 bug).
#define DECLXY(i) \
  float4 X##i = make_float4(cont[(size_t)(4 * i + 0) * NPIX + p0],        \
                            cont[(size_t)(4 * i + 1) * NPIX + p0],        \
                            cont[(size_t)(4 * i + 2) * NPIX + p0],        \
                            cont[(size_t)(4 * i + 3) * NPIX + p0]);      \
  float4 Y##i = make_float4(cont[(size_t)(4 * i + 0) * NPIX + p1],        \
                            cont[(size_t)(4 * i + 1) * NPIX + p1],        \
                            cont[(size_t)(4 * i + 2) * NPIX + p1],        \
                            cont[(size_t)(4 * i + 3) * NPIX + p1]);
  DECLXY(0)  DECLXY(1)  DECLXY(2)  DECLXY(3)
  DECLXY(4)  DECLXY(5)  DECLXY(6)  DECLXY(7)
  DECLXY(8)  DECLXY(9)  DECLXY(10) DECLXY(11)
  DECLXY(12) DECLXY(13) DECLXY(14) DECLXY(15)
#undef DECLXY

#define PINXY(i) asm volatile("" ::                                       \
    "v"(X##i.x), "v"(X##i.y), "v"(X##i.z), "v"(X##i.w),                   \
    "v"(Y##i.x), "v"(Y##i.y), "v"(Y##i.z), "v"(Y##i.w));
  PINXY(0)  PINXY(1)  PINXY(2)  PINXY(3)
  PINXY(4)  PINXY(5)  PINXY(6)  PINXY(7)
  PINXY(8)  PINXY(9)  PINXY(10) PINXY(11)
  PINXY(12) PINXY(13) PINXY(14) PINXY(15)
#undef PINXY

#define ACC2(i) {                                                         \
    const float4 tv =                                                     \
        *reinterpret_cast<const float4*>(&Trow[oc16 * 64 + 4 * i]);       \
    sa += tv.x * X##i.x + tv.y * X##i.y;                                  \
    sb += tv.z * X##i.z + tv.w * X##i.w;                                  \
    ta += tv.x * Y##i.x + tv.y * Y##i.y;                                  \
    tb += tv.z * Y##i.z + tv.w * Y##i.w; }

  const float* Tsrc = ws + offT(nblk);
  for (int q = 0; q < 4; ++q) {
    __syncthreads();
    #pragma unroll
    for (int ii = 0; ii < 4; ++ii) {
      const int f = tid + 512 * ii;          // 2048 float4 = 8 labels x 256
      const int ll = f >> 8;
      const int e4 = (f & 255) * 4;
      *reinterpret_cast<float4*>(&Tq[ll * 1028 + e4]) =
          *reinterpret_cast<const float4*>(&Tsrc[(size_t)ll * 4096 + q * 1024 + e4]);
    }
    __syncthreads();
    if (act) {
      const float* Trow = &Tq[lab * 1028];
      #pragma unroll 2
      for (int oc16 = 0; oc16 < 16; ++oc16) {
        float sa = 0.f, sb = 0.f, ta = 0.f, tb = 0.f;
        ACC2(0)  ACC2(1)  ACC2(2)  ACC2(3)
        ACC2(4)  ACC2(5)  ACC2(6)  ACC2(7)
        ACC2(8)  ACC2(9)  ACC2(10) ACC2(11)
        ACC2(12) ACC2(13) ACC2(14) ACC2(15)
        const int oc = q * 16 + oc16;
        const float bs = biasS[lab * 66 + oc];
        out[(size_t)oc * NPIX + p0] = sa + sb + bs;
        out[(size_t)oc * NPIX + p1] = ta + tb + bs;
      }
    }
  }
#undef ACC2
}

// =====================================================================
extern "C" void kernel_launch(void* const* d_in, const int* in_sizes, int n_in,
                              void* d_out, int out_size, void* d_ws, size_t ws_size,
                              hipStream_t stream)
{
  const float* cont = (const float*)d_in[0];
  const float* styl = (const float*)d_in[1];
  const int*   cseg = (const int*)d_in[2];
  const int*   sseg = (const int*)d_in[3];
  float*       ws   = (float*)d_ws;
  float*       out  = (float*)d_out;

  const size_t favail = ws_size / 4;
  int nblk = 256;   // 512 blocks -> 2 blocks/CU -> 4 waves/SIMD (falls back if ws small)
  while (nblk > 8 && offVALID(nblk) + 8 > favail) nblk >>= 1;

  k_moments<<<dim3(nblk, 2), 512, 0, stream>>>(cont, styl, cseg, sseg, ws, nblk);
  // zero MR+SR+CR (atomic accumulation targets of k_reduce)
  hipMemsetAsync(ws + offMR(nblk), 0,
                 (offWH(nblk) - offMR(nblk)) * sizeof(float), stream);
  k_reduce<<<dim3(256, 8), 256, 0, stream>>>(ws, nblk);
  k_ns<<<dim3(16), 512, 0, stream>>>(ws, nblk);
  k_tmat<<<dim3(8), 256, 0, stream>>>(ws, nblk);
  k_apply<<<dim3(NPIX / 512), 512, 0, stream>>>(cont, cseg, ws, out, nblk);
}

// Round 14
// 384.594 us; speedup vs baseline: 1.0046x; 1.0046x over previous
//
#include <hip/hip_runtime.h>
#include <math.h>

constexpr int NPIX  = 262144;   // 512*512
constexpr int NLAB  = 8;
constexpr int NITER = 5;        // Newton-Schulz iterations (e0<=0.6 -> e5 < 1e-10)

// ---------------- workspace layout (float offsets), runtime nblk ----------------
__host__ __device__ inline size_t offMpart()         { return 0; }
__host__ __device__ inline size_t offSpart(int nblk) { return (size_t)2*nblk*8*4096; }
__host__ __device__ inline size_t offCnt(int nblk)   { return offSpart(nblk) + (size_t)2*nblk*8*64; }
__host__ __device__ inline size_t offMR(int nblk)    { return offCnt(nblk) + (size_t)2*nblk*8; }
__host__ __device__ inline size_t offSR(int nblk)    { return offMR(nblk) + 2*8*4096; }
__host__ __device__ inline size_t offCR(int nblk)    { return offSR(nblk) + 2*8*64; }
__host__ __device__ inline size_t offWH(int nblk)    { return offCR(nblk) + 16; }
__host__ __device__ inline size_t offCO(int nblk)    { return offWH(nblk) + 8*4096; }
__host__ __device__ inline size_t offT(int nblk)     { return offCO(nblk) + 8*4096; }
__host__ __device__ inline size_t offBIAS(int nblk)  { return offT(nblk) + 8*4096; }
__host__ __device__ inline size_t offMUC(int nblk)   { return offBIAS(nblk) + 8*64; }
__host__ __device__ inline size_t offMUS(int nblk)   { return offMUC(nblk) + 8*64; }
__host__ __device__ inline size_t offVALID(int nblk) { return offMUS(nblk) + 8*64; }

// =====================================================================
// K1: single-pass per-label moments. grid (nblk, 2 tensors), block 512.
// 8 waves/block; wave w owns label w's 64x64 accumulator (8x8/lane).
// Pixels staged 256/phase into xs[px][64] with XOR-4 column swizzle so
// staging writes are 4-way and compute b128 reads are 2-way (free).
// Single pixel per ballot iteration (~122 live VGPR; launch_bounds(512,2)
// caps at 256 VGPR / 1 block/CU min — NOTE r8's "128 cap" claim was
// wrong: 2nd arg is waves/EU, so (512,2)=8 waves/CU=256 VGPR cap).
// =====================================================================
__global__ __launch_bounds__(512, 2) void k_moments(
    const float* __restrict__ cont, const float* __restrict__ styl,
    const int* __restrict__ cseg, const int* __restrict__ sseg,
    float* __restrict__ ws, int nblk)
{
  const int t = blockIdx.y, blk = blockIdx.x;
  const float* __restrict__ X  = t ? styl : cont;
  const int*  __restrict__ seg = t ? sseg : cseg;
  const int tid = threadIdx.x, lane = tid & 63, wv = tid >> 6;

  __shared__ float xs[256 * 64];   // exactly 64 KB

  const int r0 = (lane >> 3) << 3;
  const int c0 = (lane & 7) << 3;

  float acc[8][8];
  #pragma unroll
  for (int i = 0; i < 8; ++i)
    #pragma unroll
    for (int j = 0; j < 8; ++j) acc[i][j] = 0.f;
  float ssum = 0.f;
  int   cnt  = 0;

  const int chunk = NPIX / nblk;
  const int pbase = blk * chunk;
  const int nph   = chunk >> 8;
  const int ci  = tid >> 5;             // 0..15
  const int pxi = (tid & 31) << 2;      // 0..124
  const int swW = (tid & 7) << 2;       // staging column swizzle (bits 2..4)

  for (int ph = 0; ph < nph; ++ph) {
    const int p0 = pbase + (ph << 8);
    float4 v[8];
    #pragma unroll
    for (int q = 0; q < 8; ++q) {
      const int c  = ci + ((q & 3) << 4);
      const int px = pxi + ((q >> 2) << 7);
      v[q] = *reinterpret_cast<const float4*>(&X[(size_t)c * NPIX + p0 + px]);
    }
    int lb[4];
    #pragma unroll
    for (int g = 0; g < 4; ++g) lb[g] = seg[p0 + (g << 6) + lane];

    __syncthreads();   // previous phase reads done
    #pragma unroll
    for (int q = 0; q < 8; ++q) {
      const int c  = ci + ((q & 3) << 4);
      const int px = pxi + ((q >> 2) << 7);
      const int pc = c ^ swW;
      xs[(px + 0) * 64 + pc] = v[q].x;
      xs[(px + 1) * 64 + pc] = v[q].y;
      xs[(px + 2) * 64 + pc] = v[q].z;
      xs[(px + 3) * 64 + pc] = v[q].w;
    }
    __syncthreads();   // staging visible

    for (int g = 0; g < 4; ++g) {
      unsigned long long m = __ballot(lb[g] == wv);
      cnt += __popcll(m);
      while (m) {
        const int j = (g << 6) + __builtin_ctzll(m);
        m &= m - 1;
        const int sw = j & 28;           // ((j>>2)&7)<<2
        const float4 a0 = *reinterpret_cast<const float4*>(&xs[j * 64 + (r0 ^ sw)]);
        const float4 a1 = *reinterpret_cast<const float4*>(&xs[j * 64 + ((r0 ^ sw) ^ 4)]);
        const float4 b0 = *reinterpret_cast<const float4*>(&xs[j * 64 + (c0 ^ sw)]);
        const float4 b1 = *reinterpret_cast<const float4*>(&xs[j * 64 + ((c0 ^ sw) ^ 4)]);
        ssum += xs[j * 64 + (lane ^ sw)];
        const float av[8] = {a0.x, a0.y, a0.z, a0.w, a1.x, a1.y, a1.z, a1.w};
        const float bv[8] = {b0.x, b0.y, b0.z, b0.w, b1.x, b1.y, b1.z, b1.w};
        #pragma unroll
        for (int i = 0; i < 8; ++i)
          #pragma unroll
          for (int jj = 0; jj < 8; ++jj) acc[i][jj] += av[i] * bv[jj];
      }
    }
  }

  // flush partials (logical indexing)
  float* Md = ws + offMpart() + (size_t)((t * nblk + blk) * 8 + wv) * 4096;
  #pragma unroll
  for (int i = 0; i < 8; ++i) {
    *reinterpret_cast<float4*>(&Md[(r0 + i) * 64 + c0]) =
        make_float4(acc[i][0], acc[i][1], acc[i][2], acc[i][3]);
    *reinterpret_cast<float4*>(&Md[(r0 + i) * 64 + c0 + 4]) =
        make_float4(acc[i][4], acc[i][5], acc[i][6], acc[i][7]);
  }
  ws[offSpart(nblk) + (size_t)((t * nblk + blk) * 8 + wv) * 64 + lane] = ssum;
  if (lane == 0) ws[offCnt(nblk) + (size_t)(t * nblk + blk) * 8 + wv] = (float)cnt;
}

// =====================================================================
// K1b: reduce partials over nblk. grid (256, 8 chunks) = 2048 blocks,
// 4 independent accumulators, atomicAdd combine (MR/SR/CR pre-zeroed).
// r9: 123us -> off top-5.
// =====================================================================
__global__ __launch_bounds__(256) void k_reduce(float* __restrict__ ws, int nblk)
{
  const int b = blockIdx.x;
  const int sgm = b & 15, tl = b >> 4, l = tl & 7, t = tl >> 3;
  const int tid = threadIdx.x;
  const int clen = nblk >> 3;                 // nblk is pow2 >= 8
  const int c0 = blockIdx.y * clen, c1 = c0 + clen;
  const size_t stride = (size_t)8 * 4096;
  const float* src = ws + offMpart() + (size_t)(t * nblk) * stride + (size_t)l * 4096 + sgm * 256 + tid;
  float s0 = 0.f, s1 = 0.f, s2 = 0.f, s3 = 0.f;
  int bb = c0;
  for (; bb + 3 < c1; bb += 4) {
    s0 += src[(size_t)(bb + 0) * stride];
    s1 += src[(size_t)(bb + 1) * stride];
    s2 += src[(size_t)(bb + 2) * stride];
    s3 += src[(size_t)(bb + 3) * stride];
  }
  for (; bb < c1; ++bb) s0 += src[(size_t)bb * stride];
  atomicAdd(&ws[offMR(nblk) + (size_t)tl * 4096 + sgm * 256 + tid], (s0 + s1) + (s2 + s3));
  if (sgm == 0) {
    if (tid < 64) {
      float q0 = 0.f, q1 = 0.f;
      int b2 = c0;
      for (; b2 + 1 < c1; b2 += 2) {
        q0 += ws[offSpart(nblk) + (size_t)((t * nblk + b2) * 8 + l) * 64 + tid];
        q1 += ws[offSpart(nblk) + (size_t)((t * nblk + b2 + 1) * 8 + l) * 64 + tid];
      }
      for (; b2 < c1; ++b2)
        q0 += ws[offSpart(nblk) + (size_t)((t * nblk + b2) * 8 + l) * 64 + tid];
      atomicAdd(&ws[offSR(nblk) + tl * 64 + tid], q0 + q1);
    } else if (tid == 64) {
      float q = 0.f;
      for (int b2 = c0; b2 < c1; ++b2)
        q += ws[offCnt(nblk) + (size_t)(t * nblk + b2) * 8 + l];
      atomicAdd(&ws[offCR(nblk) + tl], q);
    }
  }
}

// =====================================================================
// 64x64 matmul, operands symmetric (A[r][k] read as A[k][r], row-k b128).
// Block 512 (8 waves -> 2 waves/SIMD for latency hiding).
// Each lane owns a 2x4 tile: rows r0,r0+1, cols c0..c0+3.
// =====================================================================
__device__ __forceinline__ void mm64x8(float* __restrict__ dst,
    const float* __restrict__ A, const float* __restrict__ B,
    int tid, float p0, float p1)
{
  const int r0 = (tid >> 4) << 1;       // 0,2,...,62
  const int c0 = (tid & 15) << 2;       // 0,4,...,60
  float acc[2][4];
  #pragma unroll
  for (int i = 0; i < 2; ++i)
    #pragma unroll
    for (int j = 0; j < 4; ++j) acc[i][j] = 0.f;
  #pragma unroll 4
  for (int k = 0; k < 64; ++k) {
    const float2 a = *reinterpret_cast<const float2*>(&A[k * 64 + r0]);
    const float4 b = *reinterpret_cast<const float4*>(&B[k * 64 + c0]);
    acc[0][0] += a.x * b.x; acc[0][1] += a.x * b.y;
    acc[0][2] += a.x * b.z; acc[0][3] += a.x * b.w;
    acc[1][0] += a.y * b.x; acc[1][1] += a.y * b.y;
    acc[1][2] += a.y * b.z; acc[1][3] += a.y * b.w;
  }
  #pragma unroll
  for (int i = 0; i < 2; ++i) {
    float4 o;
    o.x = p1 * acc[i][0] + (((r0 + i) == (c0 + 0)) ? p0 : 0.f);
    o.y = p1 * acc[i][1] + (((r0 + i) == (c0 + 1)) ? p0 : 0.f);
    o.z = p1 * acc[i][2] + (((r0 + i) == (c0 + 2)) ? p0 : 0.f);
    o.w = p1 * acc[i][3] + (((r0 + i) == (c0 + 3)) ? p0 : 0.f);
    *reinterpret_cast<float4*>(&dst[(r0 + i) * 64 + c0]) = o;
  }
}

// =====================================================================
// K2: cov build + coupled Newton-Schulz. grid 16 (t*8+l), block 512.
// t=0: WH = (cov_c+I)^-1/2 ; t=1: CO = cov_s^1/2
// =====================================================================
__global__ __launch_bounds__(512) void k_ns(float* __restrict__ ws, int nblk)
{
  const int l = blockIdx.x & 7, t = blockIdx.x >> 3;
  const int tid = threadIdx.x;
  __shared__ float bA[4096], bY[4096], bZ[4096], bT[4096];  // exactly 64 KB
  float* svec   = bT;        // scratch aliases, consumed before chain starts
  float* scal   = bT + 128;

  const float n0 = ws[offCR(nblk) + l];
  const float n1 = ws[offCR(nblk) + 8 + l];
  const float n = t ? n1 : n0;
  const bool valid = (n0 > 10.f) && (n1 > 10.f) && (n0 < 100.f * n1) && (n1 < 100.f * n0);
  if (tid < 64) svec[tid] = ws[offSR(nblk) + (t * 8 + l) * 64 + tid];
  __syncthreads();

  const float invn = 1.f / fmaxf(n, 1.f);
  const float nm1  = n - 1.f;
  const float rdiv = 1.f / ((nm1 == 0.f) ? 1e-5f : nm1);
  const int i0 = tid >> 3, jb = (tid & 7) << 3;   // 512 threads: 8 floats each
  const float Si = svec[i0];
  const float* MRp = ws + offMR(nblk) + (size_t)(t * 8 + l) * 4096;
  #pragma unroll
  for (int q = 0; q < 2; ++q) {
    const int j = jb + (q << 2);
    const float4 m  = *reinterpret_cast<const float4*>(&MRp[i0 * 64 + j]);
    const float4 sj = *reinterpret_cast<const float4*>(&svec[j]);
    float4 a;
    a.x = (m.x - Si * sj.x * invn) * rdiv + ((t == 0 && i0 == j + 0) ? 1.f : 0.f);
    a.y = (m.y - Si * sj.y * invn) * rdiv + ((t == 0 && i0 == j + 1) ? 1.f : 0.f);
    a.z = (m.z - Si * sj.z * invn) * rdiv + ((t == 0 && i0 == j + 2) ? 1.f : 0.f);
    a.w = (m.w - Si * sj.w * invn) * rdiv + ((t == 0 && i0 == j + 3) ? 1.f : 0.f);
    *reinterpret_cast<float4*>(&bA[i0 * 64 + j]) = a;
  }
  if (tid < 64) ws[(t ? offMUS(nblk) : offMUC(nblk)) + l * 64 + tid] = svec[tid] * invn;
  if (t == 0 && tid == 0) ws[offVALID(nblk) + l] = valid ? 1.f : 0.f;
  __syncthreads();

  if (tid < 64) {   // Gershgorin row sums (column read, bA exactly symmetric)
    float s = 0.f;
    for (int j = 0; j < 64; ++j) s += fabsf(bA[j * 64 + tid]);
    #pragma unroll
    for (int o = 32; o; o >>= 1) s = fmaxf(s, __shfl_xor(s, o));  // wave-parallel max
    if (tid == 0) scal[0] = fmaxf(s, 1e-20f);
  }
  __syncthreads();
  const float cval = scal[0];
  const float rc = 1.f / cval;

  #pragma unroll
  for (int q = 0; q < 2; ++q) {   // Y = A/c, Z = I
    const int j = jb + (q << 2);
    float4 a = *reinterpret_cast<const float4*>(&bA[i0 * 64 + j]);
    a.x *= rc; a.y *= rc; a.z *= rc; a.w *= rc;
    *reinterpret_cast<float4*>(&bY[i0 * 64 + j]) = a;
    float4 z;
    z.x = (i0 == j + 0) ? 1.f : 0.f; z.y = (i0 == j + 1) ? 1.f : 0.f;
    z.z = (i0 == j + 2) ? 1.f : 0.f; z.w = (i0 == j + 3) ? 1.f : 0.f;
    *reinterpret_cast<float4*>(&bZ[i0 * 64 + j]) = z;
  }
  __syncthreads();

  float *Y = bY, *Z = bZ, *T = bT, *Wb = bA;
  for (int it = 0; it < NITER; ++it) {
    mm64x8(T, Z, Y, tid, 1.5f, -0.5f); __syncthreads();
    mm64x8(Wb, Y, T, tid, 0.f, 1.f);   __syncthreads();
    mm64x8(Y, T, Z, tid, 0.f, 1.f);    __syncthreads();
    float* nz = Y; Y = Wb; Wb = Z; Z = nz;
  }

  const float osc = t ? sqrtf(cval) : (1.0f / sqrtf(cval));
  const float* src = t ? Y : Z;
  float* dst = ws + (t ? offCO(nblk) : offWH(nblk)) + (size_t)l * 4096;
  #pragma unroll
  for (int q = 0; q < 2; ++q) {
    const int j = jb + (q << 2);
    float4 v = *reinterpret_cast<const float4*>(&src[i0 * 64 + j]);
    v.x *= osc; v.y *= osc; v.z *= osc; v.w *= osc;
    *reinterpret_cast<float4*>(&dst[i0 * 64 + j]) = v;
  }
}

// =====================================================================
// K2b: T_l = CO_l @ WH_l (identity if invalid), bias_l = mus - T@muc (0 if invalid)
// =====================================================================
__global__ __launch_bounds__(256) void k_tmat(float* __restrict__ ws, int nblk)
{
  const int l = blockIdx.x;
  const int tid = threadIdx.x;
  __shared__ float Am[4096], Bm[4096];
  __shared__ float red[64];
  __shared__ float mucS[64], musS[64];
  const bool valid = ws[offVALID(nblk) + l] > 0.5f;
  if (tid < 64) {
    red[tid] = 0.f;
    mucS[tid] = ws[offMUC(nblk) + l * 64 + tid];
    musS[tid] = ws[offMUS(nblk) + l * 64 + tid];
  }
  #pragma unroll
  for (int q = 0; q < 4; ++q) {
    const int e = tid * 4 + q * 1024;
    *reinterpret_cast<float4*>(&Am[e]) =
        *reinterpret_cast<const float4*>(&ws[offCO(nblk) + (size_t)l * 4096 + e]);
    *reinterpret_cast<float4*>(&Bm[e]) =
        *reinterpret_cast<const float4*>(&ws[offWH(nblk) + (size_t)l * 4096 + e]);
  }
  __syncthreads();
  const int lane = tid & 63, wv = tid >> 6;
  const int r0 = (wv << 4) + ((lane >> 4) << 2);
  const int c0 = (lane & 15) << 2;
  float acc[4][4];
  #pragma unroll
  for (int i = 0; i < 4; ++i)
    #pragma unroll
    for (int j = 0; j < 4; ++j) acc[i][j] = 0.f;
  #pragma unroll 4
  for (int k = 0; k < 64; ++k) {
    const float4 a = *reinterpret_cast<const float4*>(&Am[k * 64 + r0]);  // CO symmetric
    const float4 b = *reinterpret_cast<const float4*>(&Bm[k * 64 + c0]);
    const float av[4] = {a.x, a.y, a.z, a.w};
    const float bv[4] = {b.x, b.y, b.z, b.w};
    #pragma unroll
    for (int i = 0; i < 4; ++i)
      #pragma unroll
      for (int j = 0; j < 4; ++j) acc[i][j] += av[i] * bv[j];
  }
  float* Td = ws + offT(nblk) + (size_t)l * 4096;
  #pragma unroll
  for (int i = 0; i < 4; ++i) {
    float4 o;
    o.x = valid ? acc[i][0] : (((r0 + i) == (c0 + 0)) ? 1.f : 0.f);
    o.y = valid ? acc[i][1] : (((r0 + i) == (c0 + 1)) ? 1.f : 0.f);
    o.z = valid ? acc[i][2] : (((r0 + i) == (c0 + 2)) ? 1.f : 0.f);
    o.w = valid ? acc[i][3] : (((r0 + i) == (c0 + 3)) ? 1.f : 0.f);
    *reinterpret_cast<float4*>(&Td[(r0 + i) * 64 + c0]) = o;
    const float bp = o.x * mucS[c0] + o.y * mucS[c0 + 1] + o.z * mucS[c0 + 2] + o.w * mucS[c0 + 3];
    atomicAdd(&red[r0 + i], bp);
  }
  __syncthreads();
  if (tid < 64) ws[offBIAS(nblk) + l * 64 + tid] = valid ? (musS[tid] - red[tid]) : 0.f;
}

// =====================================================================
// K3: apply y = T_lab x + bias_lab. Same-label PAIRS via counting sort
// (512-px window, grid exactly 512). r11/r12 history: compiler sank the
// 32 float4 loads into the q-loop (VGPR=88, 4x uncoalesced re-load);
// a "v"-input asm pin did NOT stop remat (r12: identical counters).
// r13 fix: "+v" READ-WRITE pins — compiler must assume the asm changed
// the values, so re-loading from memory is illegal -> forced residency.
// launch_bounds(512,2) caps at 256 VGPR, so ~170 fits without spill.
// Expect VGPR >=160, FETCH unchanged (~34MB), dur ~65-75us.
// Fallback if falsified: r10 1-px k_apply (98us measured).
// =====================================================================
__global__ __launch_bounds__(512, 2) void k_apply(
    const float* __restrict__ cont, const int* __restrict__ cseg,
    const float* __restrict__ ws, float* __restrict__ out, int nblk)
{
  const int tid = threadIdx.x;
  const int base = blockIdx.x * 512;
  __shared__ float Tq[8 * 1028];       // one 16-oc quarter, 8 labels
  __shared__ float biasS[8 * 66];
  __shared__ int labw[512];
  __shared__ unsigned short sidx[520];
  __shared__ int cnt8[8], cur8[8], offs8[8], npS;

  if (tid < 8) cnt8[tid] = 0;
  biasS[(tid >> 6) * 66 + (tid & 63)] = ws[offBIAS(nblk) + tid];
  __syncthreads();
  {
    const int lb = cseg[base + tid];
    labw[tid] = lb;
    atomicAdd(&cnt8[lb], 1);
  }
  __syncthreads();
  if (tid == 0) {
    int off = 0;
    for (int l2 = 0; l2 < 8; ++l2) {
      offs8[l2] = off; cur8[l2] = off;
      off += cnt8[l2] + (cnt8[l2] & 1);
    }
    npS = off >> 1;
  }
  __syncthreads();
  {
    const int pos = atomicAdd(&cur8[labw[tid]], 1);
    sidx[pos] = (unsigned short)tid;
  }
  __syncthreads();
  if (tid < 8 && (cnt8[tid] & 1))
    sidx[offs8[tid] + cnt8[tid]] = sidx[offs8[tid]];   // duplicate-pad odd runs
  __syncthreads();

  const int np = npS;                  // 256..260
  const bool act = tid < np;
  int p0 = base, p1 = base, lab = 0;
  if (act) {
    const int i0 = sidx[2 * tid], i1 = sidx[2 * tid + 1];
    lab = labw[i0];
    p0 = base + i0; p1 = base + i1;
  }

  // x vectors for both pixels as 32 NAMED float4s — loads unconditional
  // (inactive threads read pixel `base`, harmless), then pinned with
  // "+v" READ-WRITE asm so remat/re-load is illegal (r12's "v" input
  // pin failed: values were still reloadable after the sequence point).
#define DECLXY(i) \
  float4 X##i = make_float4(cont[(size_t)(4 * i + 0) * NPIX + p0],        \
                            cont[(size_t)(4 * i + 1) * NPIX + p0],        \
                            cont[(size_t)(4 * i + 2) * NPIX + p0],        \
                            cont[(size_t)(4 * i + 3) * NPIX + p0]);      \
  float4 Y##i = make_float4(cont[(size_t)(4 * i + 0) * NPIX + p1],        \
                            cont[(size_t)(4 * i + 1) * NPIX + p1],        \
                            cont[(size_t)(4 * i + 2) * NPIX + p1],        \
                            cont[(size_t)(4 * i + 3) * NPIX + p1]);
  DECLXY(0)  DECLXY(1)  DECLXY(2)  DECLXY(3)
  DECLXY(4)  DECLXY(5)  DECLXY(6)  DECLXY(7)
  DECLXY(8)  DECLXY(9)  DECLXY(10) DECLXY(11)
  DECLXY(12) DECLXY(13) DECLXY(14) DECLXY(15)
#undef DECLXY

#define PINXY(i) asm volatile("" :                                        \
    "+v"(X##i.x), "+v"(X##i.y), "+v"(X##i.z), "+v"(X##i.w),               \
    "+v"(Y##i.x), "+v"(Y##i.y), "+v"(Y##i.z), "+v"(Y##i.w));
  PINXY(0)  PINXY(1)  PINXY(2)  PINXY(3)
  PINXY(4)  PINXY(5)  PINXY(6)  PINXY(7)
  PINXY(8)  PINXY(9)  PINXY(10) PINXY(11)
  PINXY(12) PINXY(13) PINXY(14) PINXY(15)
#undef PINXY

#define ACC2(i) {                                                         \
    const float4 tv =                                                     \
        *reinterpret_cast<const float4*>(&Trow[oc16 * 64 + 4 * i]);       \
    sa += tv.x * X##i.x + tv.y * X##i.y;                                  \
    sb += tv.z * X##i.z + tv.w * X##i.w;                                  \
    ta += tv.x * Y##i.x + tv.y * Y##i.y;                                  \
    tb += tv.z * Y##i.z + tv.w * Y##i.w; }

  const float* Tsrc = ws + offT(nblk);
  for (int q = 0; q < 4; ++q) {
    __syncthreads();
    #pragma unroll
    for (int ii = 0; ii < 4; ++ii) {
      const int f = tid + 512 * ii;          // 2048 float4 = 8 labels x 256
      const int ll = f >> 8;
      const int e4 = (f & 255) * 4;
      *reinterpret_cast<float4*>(&Tq[ll * 1028 + e4]) =
          *reinterpret_cast<const float4*>(&Tsrc[(size_t)ll * 4096 + q * 1024 + e4]);
    }
    __syncthreads();
    if (act) {
      const float* Trow = &Tq[lab * 1028];
      #pragma unroll 2
      for (int oc16 = 0; oc16 < 16; ++oc16) {
        float sa = 0.f, sb = 0.f, ta = 0.f, tb = 0.f;
        ACC2(0)  ACC2(1)  ACC2(2)  ACC2(3)
        ACC2(4)  ACC2(5)  ACC2(6)  ACC2(7)
        ACC2(8)  ACC2(9)  ACC2(10) ACC2(11)
        ACC2(12) ACC2(13) ACC2(14) ACC2(15)
        const int oc = q * 16 + oc16;
        const float bs = biasS[lab * 66 + oc];
        out[(size_t)oc * NPIX + p0] = sa + sb + bs;
        out[(size_t)oc * NPIX + p1] = ta + tb + bs;
      }
    }
  }
#undef ACC2
}

// =====================================================================
extern "C" void kernel_launch(void* const* d_in, const int* in_sizes, int n_in,
                              void* d_out, int out_size, void* d_ws, size_t ws_size,
                              hipStream_t stream)
{
  const float* cont = (const float*)d_in[0];
  const float* styl = (const float*)d_in[1];
  const int*   cseg = (const int*)d_in[2];
  const int*   sseg = (const int*)d_in[3];
  float*       ws   = (float*)d_ws;
  float*       out  = (float*)d_out;

  const size_t favail = ws_size / 4;
  int nblk = 256;   // 512 blocks -> 2 blocks/CU -> 4 waves/SIMD (falls back if ws small)
  while (nblk > 8 && offVALID(nblk) + 8 > favail) nblk >>= 1;

  k_moments<<<dim3(nblk, 2), 512, 0, stream>>>(cont, styl, cseg, sseg, ws, nblk);
  // zero MR+SR+CR (atomic accumulation targets of k_reduce)
  hipMemsetAsync(ws + offMR(nblk), 0,
                 (offWH(nblk) - offMR(nblk)) * sizeof(float), stream);
  k_reduce<<<dim3(256, 8), 256, 0, stream>>>(ws, nblk);
  k_ns<<<dim3(16), 512, 0, stream>>>(ws, nblk);
  k_tmat<<<dim3(8), 256, 0, stream>>>(ws, nblk);
  k_apply<<<dim3(NPIX / 512), 512, 0, stream>>>(cont, cseg, ws, out, nblk);
}

// Round 17
// 351.839 us; speedup vs baseline: 1.0981x; 1.0931x over previous
//
#include <hip/hip_runtime.h>
#include <math.h>

constexpr int NPIX  = 262144;   // 512*512
constexpr int NLAB  = 8;
constexpr int NITER = 5;        // Newton-Schulz iterations (e0<=0.6 -> e5 < 1e-10)

// ---------------- workspace layout (float offsets), runtime nblk ----------------
__host__ __device__ inline size_t offMpart()         { return 0; }
__host__ __device__ inline size_t offSpart(int nblk) { return (size_t)2*nblk*8*4096; }
__host__ __device__ inline size_t offCnt(int nblk)   { return offSpart(nblk) + (size_t)2*nblk*8*64; }
__host__ __device__ inline size_t offMR(int nblk)    { return offCnt(nblk) + (size_t)2*nblk*8; }
__host__ __device__ inline size_t offSR(int nblk)    { return offMR(nblk) + 2*8*4096; }
__host__ __device__ inline size_t offCR(int nblk)    { return offSR(nblk) + 2*8*64; }
__host__ __device__ inline size_t offWH(int nblk)    { return offCR(nblk) + 16; }
__host__ __device__ inline size_t offCO(int nblk)    { return offWH(nblk) + 8*4096; }
__host__ __device__ inline size_t offT(int nblk)     { return offCO(nblk) + 8*4096; }
__host__ __device__ inline size_t offBIAS(int nblk)  { return offT(nblk) + 8*4096; }
__host__ __device__ inline size_t offMUC(int nblk)   { return offBIAS(nblk) + 8*64; }
__host__ __device__ inline size_t offMUS(int nblk)   { return offMUC(nblk) + 8*64; }
__host__ __device__ inline size_t offVALID(int nblk) { return offMUS(nblk) + 8*64; }

// =====================================================================
// K1: single-pass per-label moments. grid (nblk, 2 tensors), block 512.
// 8 waves/block; wave w owns label w's 64x64 accumulator (8x8/lane).
// Pixels staged 256/phase into xs[px][64] with XOR-4 column swizzle.
// Single pixel per ballot iteration (~122 live VGPR).
// =====================================================================
__global__ __launch_bounds__(512, 2) void k_moments(
    const float* __restrict__ cont, const float* __restrict__ styl,
    const int* __restrict__ cseg, const int* __restrict__ sseg,
    float* __restrict__ ws, int nblk)
{
  const int t = blockIdx.y, blk = blockIdx.x;
  const float* __restrict__ X  = t ? styl : cont;
  const int*  __restrict__ seg = t ? sseg : cseg;
  const int tid = threadIdx.x, lane = tid & 63, wv = tid >> 6;

  __shared__ float xs[256 * 64];   // exactly 64 KB

  const int r0 = (lane >> 3) << 3;
  const int c0 = (lane & 7) << 3;

  float acc[8][8];
  #pragma unroll
  for (int i = 0; i < 8; ++i)
    #pragma unroll
    for (int j = 0; j < 8; ++j) acc[i][j] = 0.f;
  float ssum = 0.f;
  int   cnt  = 0;

  const int chunk = NPIX / nblk;
  const int pbase = blk * chunk;
  const int nph   = chunk >> 8;
  const int ci  = tid >> 5;             // 0..15
  const int pxi = (tid & 31) << 2;      // 0..124
  const int swW = (tid & 7) << 2;       // staging column swizzle (bits 2..4)

  for (int ph = 0; ph < nph; ++ph) {
    const int p0 = pbase + (ph << 8);
    float4 v[8];
    #pragma unroll
    for (int q = 0; q < 8; ++q) {
      const int c  = ci + ((q & 3) << 4);
      const int px = pxi + ((q >> 2) << 7);
      v[q] = *reinterpret_cast<const float4*>(&X[(size_t)c * NPIX + p0 + px]);
    }
    int lb[4];
    #pragma unroll
    for (int g = 0; g < 4; ++g) lb[g] = seg[p0 + (g << 6) + lane];

    __syncthreads();   // previous phase reads done
    #pragma unroll
    for (int q = 0; q < 8; ++q) {
      const int c  = ci + ((q & 3) << 4);
      const int px = pxi + ((q >> 2) << 7);
      const int pc = c ^ swW;
      xs[(px + 0) * 64 + pc] = v[q].x;
      xs[(px + 1) * 64 + pc] = v[q].y;
      xs[(px + 2) * 64 + pc] = v[q].z;
      xs[(px + 3) * 64 + pc] = v[q].w;
    }
    __syncthreads();   // staging visible

    for (int g = 0; g < 4; ++g) {
      unsigned long long m = __ballot(lb[g] == wv);
      cnt += __popcll(m);
      while (m) {
        const int j = (g << 6) + __builtin_ctzll(m);
        m &= m - 1;
        const int sw = j & 28;           // ((j>>2)&7)<<2
        const float4 a0 = *reinterpret_cast<const float4*>(&xs[j * 64 + (r0 ^ sw)]);
        const float4 a1 = *reinterpret_cast<const float4*>(&xs[j * 64 + ((r0 ^ sw) ^ 4)]);
        const float4 b0 = *reinterpret_cast<const float4*>(&xs[j * 64 + (c0 ^ sw)]);
        const float4 b1 = *reinterpret_cast<const float4*>(&xs[j * 64 + ((c0 ^ sw) ^ 4)]);
        ssum += xs[j * 64 + (lane ^ sw)];
        const float av[8] = {a0.x, a0.y, a0.z, a0.w, a1.x, a1.y, a1.z, a1.w};
        const float bv[8] = {b0.x, b0.y, b0.z, b0.w, b1.x, b1.y, b1.z, b1.w};
        #pragma unroll
        for (int i = 0; i < 8; ++i)
          #pragma unroll
          for (int jj = 0; jj < 8; ++jj) acc[i][jj] += av[i] * bv[jj];
      }
    }
  }

  // flush partials (logical indexing)
  float* Md = ws + offMpart() + (size_t)((t * nblk + blk) * 8 + wv) * 4096;
  #pragma unroll
  for (int i = 0; i < 8; ++i) {
    *reinterpret_cast<float4*>(&Md[(r0 + i) * 64 + c0]) =
        make_float4(acc[i][0], acc[i][1], acc[i][2], acc[i][3]);
    *reinterpret_cast<float4*>(&Md[(r0 + i) * 64 + c0 + 4]) =
        make_float4(acc[i][4], acc[i][5], acc[i][6], acc[i][7]);
  }
  ws[offSpart(nblk) + (size_t)((t * nblk + blk) * 8 + wv) * 64 + lane] = ssum;
  if (lane == 0) ws[offCnt(nblk) + (size_t)(t * nblk + blk) * 8 + wv] = (float)cnt;
}

// =====================================================================
// K1b: reduce partials over nblk. grid (256, 8 chunks) = 2048 blocks,
// 4 independent accumulators, atomicAdd combine (MR/SR/CR pre-zeroed).
// r9: 123us -> off top-5.
// =====================================================================
__global__ __launch_bounds__(256) void k_reduce(float* __restrict__ ws, int nblk)
{
  const int b = blockIdx.x;
  const int sgm = b & 15, tl = b >> 4, l = tl & 7, t = tl >> 3;
  const int tid = threadIdx.x;
  const int clen = nblk >> 3;                 // nblk is pow2 >= 8
  const int c0 = blockIdx.y * clen, c1 = c0 + clen;
  const size_t stride = (size_t)8 * 4096;
  const float* src = ws + offMpart() + (size_t)(t * nblk) * stride + (size_t)l * 4096 + sgm * 256 + tid;
  float s0 = 0.f, s1 = 0.f, s2 = 0.f, s3 = 0.f;
  int bb = c0;
  for (; bb + 3 < c1; bb += 4) {
    s0 += src[(size_t)(bb + 0) * stride];
    s1 += src[(size_t)(bb + 1) * stride];
    s2 += src[(size_t)(bb + 2) * stride];
    s3 += src[(size_t)(bb + 3) * stride];
  }
  for (; bb < c1; ++bb) s0 += src[(size_t)bb * stride];
  atomicAdd(&ws[offMR(nblk) + (size_t)tl * 4096 + sgm * 256 + tid], (s0 + s1) + (s2 + s3));
  if (sgm == 0) {
    if (tid < 64) {
      float q0 = 0.f, q1 = 0.f;
      int b2 = c0;
      for (; b2 + 1 < c1; b2 += 2) {
        q0 += ws[offSpart(nblk) + (size_t)((t * nblk + b2) * 8 + l) * 64 + tid];
        q1 += ws[offSpart(nblk) + (size_t)((t * nblk + b2 + 1) * 8 + l) * 64 + tid];
      }
      for (; b2 < c1; ++b2)
        q0 += ws[offSpart(nblk) + (size_t)((t * nblk + b2) * 8 + l) * 64 + tid];
      atomicAdd(&ws[offSR(nblk) + tl * 64 + tid], q0 + q1);
    } else if (tid == 64) {
      float q = 0.f;
      for (int b2 = c0; b2 < c1; ++b2)
        q += ws[offCnt(nblk) + (size_t)(t * nblk + b2) * 8 + l];
      atomicAdd(&ws[offCR(nblk) + tl], q);
    }
  }
}

// =====================================================================
// 64x64 matmul, 256 threads (baseline mm64s4 — the r0 switch to 512-thr
// mm64x8 doubled LDS issue on the single LDS pipe: 1024 vs 512
// instr/mm; k_ns is LDS-issue-bound).
// Wave w owns rows [16w,16w+16), lane tile 4x4; operands symmetric.
// Per k per lane: 2 conflict-free b128 + 16 FMA.
// dst = p1*(A@B) + p0*I, written row-major.
// =====================================================================
__device__ __forceinline__ void mm64s4(float* __restrict__ dst,
    const float* __restrict__ A, const float* __restrict__ B,
    int tid, float p0, float p1)
{
  const int lane = tid & 63, wv = tid >> 6;
  const int r0 = (wv << 4) + ((lane >> 4) << 2);
  const int c0 = (lane & 15) << 2;
  float acc[4][4];
  #pragma unroll
  for (int i = 0; i < 4; ++i)
    #pragma unroll
    for (int j = 0; j < 4; ++j) acc[i][j] = 0.f;
  #pragma unroll 4
  for (int k = 0; k < 64; ++k) {
    const float4 a = *reinterpret_cast<const float4*>(&A[k * 64 + r0]);
    const float4 b = *reinterpret_cast<const float4*>(&B[k * 64 + c0]);
    const float av[4] = {a.x, a.y, a.z, a.w};
    const float bv[4] = {b.x, b.y, b.z, b.w};
    #pragma unroll
    for (int i = 0; i < 4; ++i)
      #pragma unroll
      for (int j = 0; j < 4; ++j) acc[i][j] += av[i] * bv[j];
  }
  #pragma unroll
  for (int i = 0; i < 4; ++i) {
    float4 o;
    o.x = p1 * acc[i][0] + (((r0 + i) == (c0 + 0)) ? p0 : 0.f);
    o.y = p1 * acc[i][1] + (((r0 + i) == (c0 + 1)) ? p0 : 0.f);
    o.z = p1 * acc[i][2] + (((r0 + i) == (c0 + 2)) ? p0 : 0.f);
    o.w = p1 * acc[i][3] + (((r0 + i) == (c0 + 3)) ? p0 : 0.f);
    *reinterpret_cast<float4*>(&dst[(r0 + i) * 64 + c0]) = o;
  }
}

// =====================================================================
// K2: cov build + coupled Newton-Schulz. grid 16 (t*8+l), block 256
// (256-thread baseline structure, proven in 457us session).
// t=0: WH = (cov_c+I)^-1/2 ; t=1: CO = cov_s^1/2
// =====================================================================
__global__ __launch_bounds__(256) void k_ns(float* __restrict__ ws, int nblk)
{
  const int l = blockIdx.x & 7, t = blockIdx.x >> 3;
  const int tid = threadIdx.x;
  __shared__ float bA[4096], bY[4096], bZ[4096], bT[4096];  // exactly 64 KB
  float* svec   = bT;        // scratch aliases, consumed before chain starts
  float* scal   = bT + 128;

  const float n0 = ws[offCR(nblk) + l];
  const float n1 = ws[offCR(nblk) + 8 + l];
  const float n = t ? n1 : n0;
  const bool valid = (n0 > 10.f) && (n1 > 10.f) && (n0 < 100.f * n1) && (n1 < 100.f * n0);
  if (tid < 64) svec[tid] = ws[offSR(nblk) + (t * 8 + l) * 64 + tid];
  __syncthreads();

  const float invn = 1.f / fmaxf(n, 1.f);
  const float nm1  = n - 1.f;
  const float rdiv = 1.f / ((nm1 == 0.f) ? 1e-5f : nm1);
  const int i0 = tid >> 2, jb = (tid & 3) << 4;   // 256 threads: 16 floats each
  const float Si = svec[i0];
  const float* MRp = ws + offMR(nblk) + (size_t)(t * 8 + l) * 4096;
  #pragma unroll
  for (int q = 0; q < 4; ++q) {
    const int j = jb + (q << 2);
    const float4 m  = *reinterpret_cast<const float4*>(&MRp[i0 * 64 + j]);
    const float4 sj = *reinterpret_cast<const float4*>(&svec[j]);
    float4 a;
    a.x = (m.x - Si * sj.x * invn) * rdiv + ((t == 0 && i0 == j + 0) ? 1.f : 0.f);
    a.y = (m.y - Si * sj.y * invn) * rdiv + ((t == 0 && i0 == j + 1) ? 1.f : 0.f);
    a.z = (m.z - Si * sj.z * invn) * rdiv + ((t == 0 && i0 == j + 2) ? 1.f : 0.f);
    a.w = (m.w - Si * sj.w * invn) * rdiv + ((t == 0 && i0 == j + 3) ? 1.f : 0.f);
    *reinterpret_cast<float4*>(&bA[i0 * 64 + j]) = a;
  }
  if (tid < 64) ws[(t ? offMUS(nblk) : offMUC(nblk)) + l * 64 + tid] = svec[tid] * invn;
  if (t == 0 && tid == 0) ws[offVALID(nblk) + l] = valid ? 1.f : 0.f;
  __syncthreads();

  if (tid < 64) {   // Gershgorin row sums (column read, bA exactly symmetric)
    float s = 0.f;
    for (int j = 0; j < 64; ++j) s += fabsf(bA[j * 64 + tid]);
    #pragma unroll
    for (int o = 32; o; o >>= 1) s = fmaxf(s, __shfl_xor(s, o));  // wave-parallel max
    if (tid == 0) scal[0] = fmaxf(s, 1e-20f);
  }
  __syncthreads();
  const float cval = scal[0];
  const float rc = 1.f / cval;

  #pragma unroll
  for (int q = 0; q < 4; ++q) {   // Y = A/c, Z = I
    const int j = jb + (q << 2);
    float4 a = *reinterpret_cast<const float4*>(&bA[i0 * 64 + j]);
    a.x *= rc; a.y *= rc; a.z *= rc; a.w *= rc;
    *reinterpret_cast<float4*>(&bY[i0 * 64 + j]) = a;
    float4 z;
    z.x = (i0 == j + 0) ? 1.f : 0.f; z.y = (i0 == j + 1) ? 1.f : 0.f;
    z.z = (i0 == j + 2) ? 1.f : 0.f; z.w = (i0 == j + 3) ? 1.f : 0.f;
    *reinterpret_cast<float4*>(&bZ[i0 * 64 + j]) = z;
  }
  __syncthreads();

  float *Y = bY, *Z = bZ, *T = bT, *Wb = bA;
  for (int it = 0; it < NITER; ++it) {
    mm64s4(T, Z, Y, tid, 1.5f, -0.5f); __syncthreads();
    mm64s4(Wb, Y, T, tid, 0.f, 1.f);   __syncthreads();
    mm64s4(Y, T, Z, tid, 0.f, 1.f);    __syncthreads();
    float* nz = Y; Y = Wb; Wb = Z; Z = nz;
  }

  const float osc = t ? sqrtf(cval) : (1.0f / sqrtf(cval));
  const float* src = t ? Y : Z;
  float* dst = ws + (t ? offCO(nblk) : offWH(nblk)) + (size_t)l * 4096;
  #pragma unroll
  for (int q = 0; q < 4; ++q) {
    const int j = jb + (q << 2);
    float4 v = *reinterpret_cast<const float4*>(&src[i0 * 64 + j]);
    v.x *= osc; v.y *= osc; v.z *= osc; v.w *= osc;
    *reinterpret_cast<float4*>(&dst[i0 * 64 + j]) = v;
  }
}

// =====================================================================
// K2b: T_l = CO_l @ WH_l (identity if invalid), bias_l = mus - T@muc (0 if invalid)
// =====================================================================
__global__ __launch_bounds__(256) void k_tmat(float* __restrict__ ws, int nblk)
{
  const int l = blockIdx.x;
  const int tid = threadIdx.x;
  __shared__ float Am[4096], Bm[4096];
  __shared__ float red[64];
  __shared__ float mucS[64], musS[64];
  const bool valid = ws[offVALID(nblk) + l] > 0.5f;
  if (tid < 64) {
    red[tid] = 0.f;
    mucS[tid] = ws[offMUC(nblk) + l * 64 + tid];
    musS[tid] = ws[offMUS(nblk) + l * 64 + tid];
  }
  #pragma unroll
  for (int q = 0; q < 4; ++q) {
    const int e = tid * 4 + q * 1024;
    *reinterpret_cast<float4*>(&Am[e]) =
        *reinterpret_cast<const float4*>(&ws[offCO(nblk) + (size_t)l * 4096 + e]);
    *reinterpret_cast<float4*>(&Bm[e]) =
        *reinterpret_cast<const float4*>(&ws[offWH(nblk) + (size_t)l * 4096 + e]);
  }
  __syncthreads();
  const int lane = tid & 63, wv = tid >> 6;
  const int r0 = (wv << 4) + ((lane >> 4) << 2);
  const int c0 = (lane & 15) << 2;
  float acc[4][4];
  #pragma unroll
  for (int i = 0; i < 4; ++i)
    #pragma unroll
    for (int j = 0; j < 4; ++j) acc[i][j] = 0.f;
  #pragma unroll 4
  for (int k = 0; k < 64; ++k) {
    const float4 a = *reinterpret_cast<const float4*>(&Am[k * 64 + r0]);  // CO symmetric
    const float4 b = *reinterpret_cast<const float4*>(&Bm[k * 64 + c0]);
    const float av[4] = {a.x, a.y, a.z, a.w};
    const float bv[4] = {b.x, b.y, b.z, b.w};
    #pragma unroll
    for (int i = 0; i < 4; ++i)
      #pragma unroll
      for (int j = 0; j < 4; ++j) acc[i][j] += av[i] * bv[j];
  }
  float* Td = ws + offT(nblk) + (size_t)l * 4096;
  #pragma unroll
  for (int i = 0; i < 4; ++i) {
    float4 o;
    o.x = valid ? acc[i][0] : (((r0 + i) == (c0 + 0)) ? 1.f : 0.f);
    o.y = valid ? acc[i][1] : (((r0 + i) == (c0 + 1)) ? 1.f : 0.f);
    o.z = valid ? acc[i][2] : (((r0 + i) == (c0 + 2)) ? 1.f : 0.f);
    o.w = valid ? acc[i][3] : (((r0 + i) == (c0 + 3)) ? 1.f : 0.f);
    *reinterpret_cast<float4*>(&Td[(r0 + i) * 64 + c0]) = o;
    const float bp = o.x * mucS[c0] + o.y * mucS[c0 + 1] + o.z * mucS[c0 + 2] + o.w * mucS[c0 + 3];
    atomicAdd(&red[r0 + i], bp);
  }
  __syncthreads();
  if (tid < 64) ws[offBIAS(nblk) + l * 64 + tid] = valid ? (musS[tid] - red[tid]) : 0.f;
}

// =====================================================================
// K3: apply y = T_lab x + bias_lab. r10-exact (98us measured).
// Pixel-per-lane, NO sort. Pairing variants (r11-r14) archived dead:
// compiler refuses 128 live floats/thread (remat or spill; both pins
// defeated). Block 512 = 512 contiguous pixels; grid 512. x[64] as
// 16 NAMED float4s (96 VGPR, resident). T staged per-quarter,
// 1028-float label stride (conflict-free). Coalesced loads/stores.
// =====================================================================
__global__ __launch_bounds__(512, 2) void k_apply(
    const float* __restrict__ cont, const int* __restrict__ cseg,
    const float* __restrict__ ws, float* __restrict__ out, int nblk)
{
  const int tid = threadIdx.x;
  const int p   = blockIdx.x * 512 + tid;
  __shared__ float Tq[8 * 1028];       // one 16-oc quarter, 8 labels
  __shared__ float biasS[8 * 66];

  biasS[(tid >> 6) * 66 + (tid & 63)] = ws[offBIAS(nblk) + tid];

  const int lab = cseg[p];

  // x[0..63] as 16 named float4s — cannot land in scratch.
#define DECLX(i) float4 X##i = make_float4(                               \
      cont[(size_t)(4 * i + 0) * NPIX + p],                               \
      cont[(size_t)(4 * i + 1) * NPIX + p],                               \
      cont[(size_t)(4 * i + 2) * NPIX + p],                               \
      cont[(size_t)(4 * i + 3) * NPIX + p]);
  DECLX(0)  DECLX(1)  DECLX(2)  DECLX(3)
  DECLX(4)  DECLX(5)  DECLX(6)  DECLX(7)
  DECLX(8)  DECLX(9)  DECLX(10) DECLX(11)
  DECLX(12) DECLX(13) DECLX(14) DECLX(15)
#undef DECLX

#define ACCX(i) {                                                         \
    const float4 tv =                                                     \
        *reinterpret_cast<const float4*>(&Trow[oc16 * 64 + 4 * i]);       \
    sa += tv.x * X##i.x + tv.y * X##i.y;                                  \
    sb += tv.z * X##i.z + tv.w * X##i.w; }

  const float* Tsrc = ws + offT(nblk);
  for (int q = 0; q < 4; ++q) {
    __syncthreads();
    #pragma unroll
    for (int ii = 0; ii < 4; ++ii) {
      const int f = tid + 512 * ii;          // 2048 float4 = 8 labels x 256
      const int ll = f >> 8;
      const int e4 = (f & 255) * 4;
      *reinterpret_cast<float4*>(&Tq[ll * 1028 + e4]) =
          *reinterpret_cast<const float4*>(&Tsrc[(size_t)ll * 4096 + q * 1024 + e4]);
    }
    __syncthreads();
    const float* Trow = &Tq[lab * 1028];
    #pragma unroll 2
    for (int oc16 = 0; oc16 < 16; ++oc16) {
      float sa = 0.f, sb = 0.f;
      ACCX(0)  ACCX(1)  ACCX(2)  ACCX(3)
      ACCX(4)  ACCX(5)  ACCX(6)  ACCX(7)
      ACCX(8)  ACCX(9)  ACCX(10) ACCX(11)
      ACCX(12) ACCX(13) ACCX(14) ACCX(15)
      const int oc = q * 16 + oc16;
      out[(size_t)oc * NPIX + p] = sa + sb + biasS[lab * 66 + oc];
    }
  }
#undef ACCX
}

// =====================================================================
extern "C" void kernel_launch(void* const* d_in, const int* in_sizes, int n_in,
                              void* d_out, int out_size, void* d_ws, size_t ws_size,
                              hipStream_t stream)
{
  const float* cont = (const float*)d_in[0];
  const float* styl = (const float*)d_in[1];
  const int*   cseg = (const int*)d_in[2];
  const int*   sseg = (const int*)d_in[3];
  float*       ws   = (float*)d_ws;
  float*       out  = (float*)d_out;

  const size_t favail = ws_size / 4;
  int nblk = 256;   // 512 blocks -> 2 blocks/CU (falls back if ws small)
  while (nblk > 8 && offVALID(nblk) + 8 > favail) nblk >>= 1;

  k_moments<<<dim3(nblk, 2), 512, 0, stream>>>(cont, styl, cseg, sseg, ws, nblk);
  // zero MR+SR+CR (atomic accumulation targets of k_reduce)
  hipMemsetAsync(ws + offMR(nblk), 0,
                 (offWH(nblk) - offMR(nblk)) * sizeof(float), stream);
  k_reduce<<<dim3(256, 8), 256, 0, stream>>>(ws, nblk);
  k_ns<<<dim3(16), 256, 0, stream>>>(ws, nblk);
  k_tmat<<<dim3(8), 256, 0, stream>>>(ws, nblk);
  k_apply<<<dim3(NPIX / 512), 512, 0, stream>>>(cont, cseg, ws, out, nblk);
}

// Round 18
// 351.728 us; speedup vs baseline: 1.0985x; 1.0003x over previous
//
#include <hip/hip_runtime.h>
#include <math.h>

constexpr int NPIX  = 262144;   // 512*512
constexpr int NLAB  = 8;
constexpr int NITER = 5;        // Newton-Schulz iterations (e0<=0.6 -> e5 < 1e-10)

// ---------------- workspace layout (float offsets), runtime nblk ----------------
__host__ __device__ inline size_t offMpart()         { return 0; }
__host__ __device__ inline size_t offSpart(int nblk) { return (size_t)2*nblk*8*4096; }
__host__ __device__ inline size_t offCnt(int nblk)   { return offSpart(nblk) + (size_t)2*nblk*8*64; }
__host__ __device__ inline size_t offMR(int nblk)    { return offCnt(nblk) + (size_t)2*nblk*8; }
__host__ __device__ inline size_t offSR(int nblk)    { return offMR(nblk) + 2*8*4096; }
__host__ __device__ inline size_t offCR(int nblk)    { return offSR(nblk) + 2*8*64; }
__host__ __device__ inline size_t offWH(int nblk)    { return offCR(nblk) + 16; }
__host__ __device__ inline size_t offCO(int nblk)    { return offWH(nblk) + 8*4096; }
__host__ __device__ inline size_t offT(int nblk)     { return offCO(nblk) + 8*4096; }
__host__ __device__ inline size_t offBIAS(int nblk)  { return offT(nblk) + 8*4096; }
__host__ __device__ inline size_t offMUC(int nblk)   { return offBIAS(nblk) + 8*64; }
__host__ __device__ inline size_t offMUS(int nblk)   { return offMUC(nblk) + 8*64; }
__host__ __device__ inline size_t offVALID(int nblk) { return offMUS(nblk) + 8*64; }

// =====================================================================
// K1: single-pass per-label moments. grid (nblk, 2 tensors), block 512.
// r18: ballot loop replaced by per-phase COUNTING SORT (machinery cloned
// from the 4x-bench-verified r10 k_apply sort). Phases shrink 256->128 px
// (xs 32KB + plist fits 64KB static LDS; 2 blocks/CU kept, ~110 VGPR).
// Wave w then iterates its label's pixel list with a KNOWN trip count:
// wave-uniform plist read (LDS broadcast), no ctz/popcll serial chain,
// compiler can unroll/prefetch across pixels. Inner body unchanged:
// 4 conflict-free b128 + 1 b32 per pixel, 64 FMA/lane.
// =====================================================================
__global__ __launch_bounds__(512, 2) void k_moments(
    const float* __restrict__ cont, const float* __restrict__ styl,
    const int* __restrict__ cseg, const int* __restrict__ sseg,
    float* __restrict__ ws, int nblk)
{
  const int t = blockIdx.y, blk = blockIdx.x;
  const float* __restrict__ X  = t ? styl : cont;
  const int*  __restrict__ seg = t ? sseg : cseg;
  const int tid = threadIdx.x, lane = tid & 63, wv = tid >> 6;

  __shared__ float xs[128 * 64];            // 32 KB staging
  __shared__ unsigned short plist[128];
  __shared__ int cnt8[8], cur8[8], offs8[8];

  const int r0 = (lane >> 3) << 3;
  const int c0 = (lane & 7) << 3;

  float acc[8][8];
  #pragma unroll
  for (int i = 0; i < 8; ++i)
    #pragma unroll
    for (int j = 0; j < 8; ++j) acc[i][j] = 0.f;
  float ssum = 0.f;
  int   cnt  = 0;

  const int chunk = NPIX / nblk;            // 1024 at nblk=256
  const int pbase = blk * chunk;
  const int nph   = chunk >> 7;             // 128-px phases
  const int ci  = tid >> 5;                 // 0..15
  const int pxi = (tid & 31) << 2;          // 0..124
  const int swW = (tid & 7) << 2;           // staging column swizzle

  for (int ph = 0; ph < nph; ++ph) {
    const int p0 = pbase + (ph << 7);
    float4 v[4];
    #pragma unroll
    for (int q = 0; q < 4; ++q) {
      const int c = ci + (q << 4);
      v[q] = *reinterpret_cast<const float4*>(&X[(size_t)c * NPIX + p0 + pxi]);
    }
    int lbv = 0;
    if (tid < 128) lbv = seg[p0 + tid];

    __syncthreads();   // previous phase reads done
    #pragma unroll
    for (int q = 0; q < 4; ++q) {
      const int c  = ci + (q << 4);
      const int pc = c ^ swW;
      xs[(pxi + 0) * 64 + pc] = v[q].x;
      xs[(pxi + 1) * 64 + pc] = v[q].y;
      xs[(pxi + 2) * 64 + pc] = v[q].z;
      xs[(pxi + 3) * 64 + pc] = v[q].w;
    }
    if (tid < 8) cnt8[tid] = 0;
    __syncthreads();   // staging + cnt zero visible

    if (tid < 128) atomicAdd(&cnt8[lbv], 1);
    __syncthreads();
    if (tid == 0) {
      int off = 0;
      for (int l2 = 0; l2 < 8; ++l2) { offs8[l2] = off; cur8[l2] = off; off += cnt8[l2]; }
    }
    __syncthreads();
    if (tid < 128) {
      const int pos = atomicAdd(&cur8[lbv], 1);
      plist[pos] = (unsigned short)tid;
    }
    __syncthreads();

    const int n  = cnt8[wv];
    const int ob = offs8[wv];
    cnt += n;
    for (int kk = 0; kk < n; ++kk) {
      const int j  = plist[ob + kk];       // wave-uniform broadcast read
      const int sw = j & 28;               // ((j>>2)&7)<<2
      const float4 a0 = *reinterpret_cast<const float4*>(&xs[j * 64 + (r0 ^ sw)]);
      const float4 a1 = *reinterpret_cast<const float4*>(&xs[j * 64 + ((r0 ^ sw) ^ 4)]);
      const float4 b0 = *reinterpret_cast<const float4*>(&xs[j * 64 + (c0 ^ sw)]);
      const float4 b1 = *reinterpret_cast<const float4*>(&xs[j * 64 + ((c0 ^ sw) ^ 4)]);
      ssum += xs[j * 64 + (lane ^ sw)];
      const float av[8] = {a0.x, a0.y, a0.z, a0.w, a1.x, a1.y, a1.z, a1.w};
      const float bv[8] = {b0.x, b0.y, b0.z, b0.w, b1.x, b1.y, b1.z, b1.w};
      #pragma unroll
      for (int i = 0; i < 8; ++i)
        #pragma unroll
        for (int jj = 0; jj < 8; ++jj) acc[i][jj] += av[i] * bv[jj];
    }
  }

  // flush partials (logical indexing)
  float* Md = ws + offMpart() + (size_t)((t * nblk + blk) * 8 + wv) * 4096;
  #pragma unroll
  for (int i = 0; i < 8; ++i) {
    *reinterpret_cast<float4*>(&Md[(r0 + i) * 64 + c0]) =
        make_float4(acc[i][0], acc[i][1], acc[i][2], acc[i][3]);
    *reinterpret_cast<float4*>(&Md[(r0 + i) * 64 + c0 + 4]) =
        make_float4(acc[i][4], acc[i][5], acc[i][6], acc[i][7]);
  }
  ws[offSpart(nblk) + (size_t)((t * nblk + blk) * 8 + wv) * 64 + lane] = ssum;
  if (lane == 0) ws[offCnt(nblk) + (size_t)(t * nblk + blk) * 8 + wv] = (float)cnt;
}

// =====================================================================
// K1b: reduce partials over nblk. grid (256, 8 chunks) = 2048 blocks,
// 4 independent accumulators, atomicAdd combine (MR/SR/CR pre-zeroed).
// =====================================================================
__global__ __launch_bounds__(256) void k_reduce(float* __restrict__ ws, int nblk)
{
  const int b = blockIdx.x;
  const int sgm = b & 15, tl = b >> 4, l = tl & 7, t = tl >> 3;
  const int tid = threadIdx.x;
  const int clen = nblk >> 3;                 // nblk is pow2 >= 8
  const int c0 = blockIdx.y * clen, c1 = c0 + clen;
  const size_t stride = (size_t)8 * 4096;
  const float* src = ws + offMpart() + (size_t)(t * nblk) * stride + (size_t)l * 4096 + sgm * 256 + tid;
  float s0 = 0.f, s1 = 0.f, s2 = 0.f, s3 = 0.f;
  int bb = c0;
  for (; bb + 3 < c1; bb += 4) {
    s0 += src[(size_t)(bb + 0) * stride];
    s1 += src[(size_t)(bb + 1) * stride];
    s2 += src[(size_t)(bb + 2) * stride];
    s3 += src[(size_t)(bb + 3) * stride];
  }
  for (; bb < c1; ++bb) s0 += src[(size_t)bb * stride];
  atomicAdd(&ws[offMR(nblk) + (size_t)tl * 4096 + sgm * 256 + tid], (s0 + s1) + (s2 + s3));
  if (sgm == 0) {
    if (tid < 64) {
      float q0 = 0.f, q1 = 0.f;
      int b2 = c0;
      for (; b2 + 1 < c1; b2 += 2) {
        q0 += ws[offSpart(nblk) + (size_t)((t * nblk + b2) * 8 + l) * 64 + tid];
        q1 += ws[offSpart(nblk) + (size_t)((t * nblk + b2 + 1) * 8 + l) * 64 + tid];
      }
      for (; b2 < c1; ++b2)
        q0 += ws[offSpart(nblk) + (size_t)((t * nblk + b2) * 8 + l) * 64 + tid];
      atomicAdd(&ws[offSR(nblk) + tl * 64 + tid], q0 + q1);
    } else if (tid == 64) {
      float q = 0.f;
      for (int b2 = c0; b2 < c1; ++b2)
        q += ws[offCnt(nblk) + (size_t)(t * nblk + b2) * 8 + l];
      atomicAdd(&ws[offCR(nblk) + tl], q);
    }
  }
}

// =====================================================================
// 64x64 matmul, 256 threads (baseline mm64s4; k_ns is LDS-issue-bound,
// 512 instr/mm vs 1024 for the 512-thr variant).
// Wave w owns rows [16w,16w+16), lane tile 4x4; operands symmetric.
// dst = p1*(A@B) + p0*I, written row-major.
// =====================================================================
__device__ __forceinline__ void mm64s4(float* __restrict__ dst,
    const float* __restrict__ A, const float* __restrict__ B,
    int tid, float p0, float p1)
{
  const int lane = tid & 63, wv = tid >> 6;
  const int r0 = (wv << 4) + ((lane >> 4) << 2);
  const int c0 = (lane & 15) << 2;
  float acc[4][4];
  #pragma unroll
  for (int i = 0; i < 4; ++i)
    #pragma unroll
    for (int j = 0; j < 4; ++j) acc[i][j] = 0.f;
  #pragma unroll 4
  for (int k = 0; k < 64; ++k) {
    const float4 a = *reinterpret_cast<const float4*>(&A[k * 64 + r0]);
    const float4 b = *reinterpret_cast<const float4*>(&B[k * 64 + c0]);
    const float av[4] = {a.x, a.y, a.z, a.w};
    const float bv[4] = {b.x, b.y, b.z, b.w};
    #pragma unroll
    for (int i = 0; i < 4; ++i)
      #pragma unroll
      for (int j = 0; j < 4; ++j) acc[i][j] += av[i] * bv[j];
  }
  #pragma unroll
  for (int i = 0; i < 4; ++i) {
    float4 o;
    o.x = p1 * acc[i][0] + (((r0 + i) == (c0 + 0)) ? p0 : 0.f);
    o.y = p1 * acc[i][1] + (((r0 + i) == (c0 + 1)) ? p0 : 0.f);
    o.z = p1 * acc[i][2] + (((r0 + i) == (c0 + 2)) ? p0 : 0.f);
    o.w = p1 * acc[i][3] + (((r0 + i) == (c0 + 3)) ? p0 : 0.f);
    *reinterpret_cast<float4*>(&dst[(r0 + i) * 64 + c0]) = o;
  }
}

// =====================================================================
// K2: cov build + coupled Newton-Schulz. grid 16 (t*8+l), block 256.
// t=0: WH = (cov_c+I)^-1/2 ; t=1: CO = cov_s^1/2
// =====================================================================
__global__ __launch_bounds__(256) void k_ns(float* __restrict__ ws, int nblk)
{
  const int l = blockIdx.x & 7, t = blockIdx.x >> 3;
  const int tid = threadIdx.x;
  __shared__ float bA[4096], bY[4096], bZ[4096], bT[4096];  // exactly 64 KB
  float* svec   = bT;        // scratch aliases, consumed before chain starts
  float* scal   = bT + 128;

  const float n0 = ws[offCR(nblk) + l];
  const float n1 = ws[offCR(nblk) + 8 + l];
  const float n = t ? n1 : n0;
  const bool valid = (n0 > 10.f) && (n1 > 10.f) && (n0 < 100.f * n1) && (n1 < 100.f * n0);
  if (tid < 64) svec[tid] = ws[offSR(nblk) + (t * 8 + l) * 64 + tid];
  __syncthreads();

  const float invn = 1.f / fmaxf(n, 1.f);
  const float nm1  = n - 1.f;
  const float rdiv = 1.f / ((nm1 == 0.f) ? 1e-5f : nm1);
  const int i0 = tid >> 2, jb = (tid & 3) << 4;   // 256 threads: 16 floats each
  const float Si = svec[i0];
  const float* MRp = ws + offMR(nblk) + (size_t)(t * 8 + l) * 4096;
  #pragma unroll
  for (int q = 0; q < 4; ++q) {
    const int j = jb + (q << 2);
    const float4 m  = *reinterpret_cast<const float4*>(&MRp[i0 * 64 + j]);
    const float4 sj = *reinterpret_cast<const float4*>(&svec[j]);
    float4 a;
    a.x = (m.x - Si * sj.x * invn) * rdiv + ((t == 0 && i0 == j + 0) ? 1.f : 0.f);
    a.y = (m.y - Si * sj.y * invn) * rdiv + ((t == 0 && i0 == j + 1) ? 1.f : 0.f);
    a.z = (m.z - Si * sj.z * invn) * rdiv + ((t == 0 && i0 == j + 2) ? 1.f : 0.f);
    a.w = (m.w - Si * sj.w * invn) * rdiv + ((t == 0 && i0 == j + 3) ? 1.f : 0.f);
    *reinterpret_cast<float4*>(&bA[i0 * 64 + j]) = a;
  }
  if (tid < 64) ws[(t ? offMUS(nblk) : offMUC(nblk)) + l * 64 + tid] = svec[tid] * invn;
  if (t == 0 && tid == 0) ws[offVALID(nblk) + l] = valid ? 1.f : 0.f;
  __syncthreads();

  if (tid < 64) {   // Gershgorin row sums (column read, bA exactly symmetric)
    float s = 0.f;
    for (int j = 0; j < 64; ++j) s += fabsf(bA[j * 64 + tid]);
    #pragma unroll
    for (int o = 32; o; o >>= 1) s = fmaxf(s, __shfl_xor(s, o));  // wave-parallel max
    if (tid == 0) scal[0] = fmaxf(s, 1e-20f);
  }
  __syncthreads();
  const float cval = scal[0];
  const float rc = 1.f / cval;

  #pragma unroll
  for (int q = 0; q < 4; ++q) {   // Y = A/c, Z = I
    const int j = jb + (q << 2);
    float4 a = *reinterpret_cast<const float4*>(&bA[i0 * 64 + j]);
    a.x *= rc; a.y *= rc; a.z *= rc; a.w *= rc;
    *reinterpret_cast<float4*>(&bY[i0 * 64 + j]) = a;
    float4 z;
    z.x = (i0 == j + 0) ? 1.f : 0.f; z.y = (i0 == j + 1) ? 1.f : 0.f;
    z.z = (i0 == j + 2) ? 1.f : 0.f; z.w = (i0 == j + 3) ? 1.f : 0.f;
    *reinterpret_cast<float4*>(&bZ[i0 * 64 + j]) = z;
  }
  __syncthreads();

  float *Y = bY, *Z = bZ, *T = bT, *Wb = bA;
  for (int it = 0; it < NITER; ++it) {
    mm64s4(T, Z, Y, tid, 1.5f, -0.5f); __syncthreads();
    mm64s4(Wb, Y, T, tid, 0.f, 1.f);   __syncthreads();
    mm64s4(Y, T, Z, tid, 0.f, 1.f);    __syncthreads();
    float* nz = Y; Y = Wb; Wb = Z; Z = nz;
  }

  const float osc = t ? sqrtf(cval) : (1.0f / sqrtf(cval));
  const float* src = t ? Y : Z;
  float* dst = ws + (t ? offCO(nblk) : offWH(nblk)) + (size_t)l * 4096;
  #pragma unroll
  for (int q = 0; q < 4; ++q) {
    const int j = jb + (q << 2);
    float4 v = *reinterpret_cast<const float4*>(&src[i0 * 64 + j]);
    v.x *= osc; v.y *= osc; v.z *= osc; v.w *= osc;
    *reinterpret_cast<float4*>(&dst[i0 * 64 + j]) = v;
  }
}

// =====================================================================
// K2b: T_l = CO_l @ WH_l (identity if invalid), bias_l = mus - T@muc (0 if invalid)
// =====================================================================
__global__ __launch_bounds__(256) void k_tmat(float* __restrict__ ws, int nblk)
{
  const int l = blockIdx.x;
  const int tid = threadIdx.x;
  __shared__ float Am[4096], Bm[4096];
  __shared__ float red[64];
  __shared__ float mucS[64], musS[64];
  const bool valid = ws[offVALID(nblk) + l] > 0.5f;
  if (tid < 64) {
    red[tid] = 0.f;
    mucS[tid] = ws[offMUC(nblk) + l * 64 + tid];
    musS[tid] = ws[offMUS(nblk) + l * 64 + tid];
  }
  #pragma unroll
  for (int q = 0; q < 4; ++q) {
    const int e = tid * 4 + q * 1024;
    *reinterpret_cast<float4*>(&Am[e]) =
        *reinterpret_cast<const float4*>(&ws[offCO(nblk) + (size_t)l * 4096 + e]);
    *reinterpret_cast<float4*>(&Bm[e]) =
        *reinterpret_cast<const float4*>(&ws[offWH(nblk) + (size_t)l * 4096 + e]);
  }
  __syncthreads();
  const int lane = tid & 63, wv = tid >> 6;
  const int r0 = (wv << 4) + ((lane >> 4) << 2);
  const int c0 = (lane & 15) << 2;
  float acc[4][4];
  #pragma unroll
  for (int i = 0; i < 4; ++i)
    #pragma unroll
    for (int j = 0; j < 4; ++j) acc[i][j] = 0.f;
  #pragma unroll 4
  for (int k = 0; k < 64; ++k) {
    const float4 a = *reinterpret_cast<const float4*>(&Am[k * 64 + r0]);  // CO symmetric
    const float4 b = *reinterpret_cast<const float4*>(&Bm[k * 64 + c0]);
    const float av[4] = {a.x, a.y, a.z, a.w};
    const float bv[4] = {b.x, b.y, b.z, b.w};
    #pragma unroll
    for (int i = 0; i < 4; ++i)
      #pragma unroll
      for (int j = 0; j < 4; ++j) acc[i][j] += av[i] * bv[j];
  }
  float* Td = ws + offT(nblk) + (size_t)l * 4096;
  #pragma unroll
  for (int i = 0; i < 4; ++i) {
    float4 o;
    o.x = valid ? acc[i][0] : (((r0 + i) == (c0 + 0)) ? 1.f : 0.f);
    o.y = valid ? acc[i][1] : (((r0 + i) == (c0 + 1)) ? 1.f : 0.f);
    o.z = valid ? acc[i][2] : (((r0 + i) == (c0 + 2)) ? 1.f : 0.f);
    o.w = valid ? acc[i][3] : (((r0 + i) == (c0 + 3)) ? 1.f : 0.f);
    *reinterpret_cast<float4*>(&Td[(r0 + i) * 64 + c0]) = o;
    const float bp = o.x * mucS[c0] + o.y * mucS[c0 + 1] + o.z * mucS[c0 + 2] + o.w * mucS[c0 + 3];
    atomicAdd(&red[r0 + i], bp);
  }
  __syncthreads();
  if (tid < 64) ws[offBIAS(nblk) + l * 64 + tid] = valid ? (musS[tid] - red[tid]) : 0.f;
}

// =====================================================================
// K3: apply y = T_lab x + bias_lab. r10-exact (98us measured; 124 in a
// slower-clock container — cross-run variance ±25%). Pixel-per-lane,
// NO sort. Pairing variants (r11-r14) archived dead (remat/spill).
// Block 512 = 512 contiguous pixels; grid 512. x[64] as 16 NAMED
// float4s (96 VGPR, resident). T staged per-quarter, 1028-float label
// stride (conflict-free). Coalesced loads/stores.
// =====================================================================
__global__ __launch_bounds__(512, 2) void k_apply(
    const float* __restrict__ cont, const int* __restrict__ cseg,
    const float* __restrict__ ws, float* __restrict__ out, int nblk)
{
  const int tid = threadIdx.x;
  const int p   = blockIdx.x * 512 + tid;
  __shared__ float Tq[8 * 1028];       // one 16-oc quarter, 8 labels
  __shared__ float biasS[8 * 66];

  biasS[(tid >> 6) * 66 + (tid & 63)] = ws[offBIAS(nblk) + tid];

  const int lab = cseg[p];

  // x[0..63] as 16 named float4s — cannot land in scratch.
#define DECLX(i) float4 X##i = make_float4(                               \
      cont[(size_t)(4 * i + 0) * NPIX + p],                               \
      cont[(size_t)(4 * i + 1) * NPIX + p],                               \
      cont[(size_t)(4 * i + 2) * NPIX + p],                               \
      cont[(size_t)(4 * i + 3) * NPIX + p]);
  DECLX(0)  DECLX(1)  DECLX(2)  DECLX(3)
  DECLX(4)  DECLX(5)  DECLX(6)  DECLX(7)
  DECLX(8)  DECLX(9)  DECLX(10) DECLX(11)
  DECLX(12) DECLX(13) DECLX(14) DECLX(15)
#undef DECLX

#define ACCX(i) {                                                         \
    const float4 tv =                                                     \
        *reinterpret_cast<const float4*>(&Trow[oc16 * 64 + 4 * i]);       \
    sa += tv.x * X##i.x + tv.y * X##i.y;                                  \
    sb += tv.z * X##i.z + tv.w * X##i.w; }

  const float* Tsrc = ws + offT(nblk);
  for (int q = 0; q < 4; ++q) {
    __syncthreads();
    #pragma unroll
    for (int ii = 0; ii < 4; ++ii) {
      const int f = tid + 512 * ii;          // 2048 float4 = 8 labels x 256
      const int ll = f >> 8;
      const int e4 = (f & 255) * 4;
      *reinterpret_cast<float4*>(&Tq[ll * 1028 + e4]) =
          *reinterpret_cast<const float4*>(&Tsrc[(size_t)ll * 4096 + q * 1024 + e4]);
    }
    __syncthreads();
    const float* Trow = &Tq[lab * 1028];
    #pragma unroll 2
    for (int oc16 = 0; oc16 < 16; ++oc16) {
      float sa = 0.f, sb = 0.f;
      ACCX(0)  ACCX(1)  ACCX(2)  ACCX(3)
      ACCX(4)  ACCX(5)  ACCX(6)  ACCX(7)
      ACCX(8)  ACCX(9)  ACCX(10) ACCX(11)
      ACCX(12) ACCX(13) ACCX(14) ACCX(15)
      const int oc = q * 16 + oc16;
      out[(size_t)oc * NPIX + p] = sa + sb + biasS[lab * 66 + oc];
    }
  }
#undef ACCX
}

// =====================================================================
extern "C" void kernel_launch(void* const* d_in, const int* in_sizes, int n_in,
                              void* d_out, int out_size, void* d_ws, size_t ws_size,
                              hipStream_t stream)
{
  const float* cont = (const float*)d_in[0];
  const float* styl = (const float*)d_in[1];
  const int*   cseg = (const int*)d_in[2];
  const int*   sseg = (const int*)d_in[3];
  float*       ws   = (float*)d_ws;
  float*       out  = (float*)d_out;

  const size_t favail = ws_size / 4;
  int nblk = 256;   // 512 blocks -> 2 blocks/CU (falls back if ws small)
  while (nblk > 8 && offVALID(nblk) + 8 > favail) nblk >>= 1;

  k_moments<<<dim3(nblk, 2), 512, 0, stream>>>(cont, styl, cseg, sseg, ws, nblk);
  // zero MR+SR+CR (atomic accumulation targets of k_reduce)
  hipMemsetAsync(ws + offMR(nblk), 0,
                 (offWH(nblk) - offMR(nblk)) * sizeof(float), stream);
  k_reduce<<<dim3(256, 8), 256, 0, stream>>>(ws, nblk);
  k_ns<<<dim3(16), 256, 0, stream>>>(ws, nblk);
  k_tmat<<<dim3(8), 256, 0, stream>>>(ws, nblk);
  k_apply<<<dim3(NPIX / 512), 512, 0, stream>>>(cont, cseg, ws, out, nblk);
}